// Round 14
// baseline (826.017 us; speedup 1.0000x reference)
//
#include <hip/hip_runtime.h>

typedef short s8v __attribute__((ext_vector_type(8)));
typedef float f32x4 __attribute__((ext_vector_type(4)));
typedef unsigned short u16;

__device__ __forceinline__ float bf2f(u16 h){
  union { unsigned u; float f; } v; v.u = ((unsigned)h) << 16; return v.f;
}
__device__ __forceinline__ u16 f2bf(float f){
  union { float f; unsigned u; } v; v.f = f;
  unsigned u = v.u;
  return (u16)((u + 0x7fffu + ((u >> 16) & 1u)) >> 16);
}
#define MFMA(a,b,c) __builtin_amdgcn_mfma_f32_16x16x32_bf16((a),(b),(c),0,0,0)

#define WREDUCE64(s) { s += __shfl_xor(s,1); s += __shfl_xor(s,2); s += __shfl_xor(s,4); \
                       s += __shfl_xor(s,8); s += __shfl_xor(s,16); s += __shfl_xor(s,32); }
#define QREDUCE16(s) { s += __shfl_xor(s,1); s += __shfl_xor(s,2); s += __shfl_xor(s,4); s += __shfl_xor(s,8); }

// 16-value butterfly within 16-lane quads: lane c (0..15) ends with sum-over-quad of val[c]
__device__ __forceinline__ float quad_butterfly16(float* val, int c){
  float v8[8], v4[4], v2[2];
  #pragma unroll
  for(int t=0;t<8;t++){
    float sent = (c&1) ? val[2*t] : val[2*t+1];
    float got = __shfl_xor(sent, 1);
    v8[t] = ((c&1) ? val[2*t+1] : val[2*t]) + got;
  }
  #pragma unroll
  for(int t=0;t<4;t++){
    float sent = ((c>>1)&1) ? v8[2*t] : v8[2*t+1];
    float got = __shfl_xor(sent, 2);
    v4[t] = (((c>>1)&1) ? v8[2*t+1] : v8[2*t]) + got;
  }
  #pragma unroll
  for(int t=0;t<2;t++){
    float sent = ((c>>2)&1) ? v4[2*t] : v4[2*t+1];
    float got = __shfl_xor(sent, 4);
    v2[t] = (((c>>2)&1) ? v4[2*t+1] : v4[2*t]) + got;
  }
  float sent = ((c>>3)&1) ? v2[0] : v2[1];
  float got = __shfl_xor(sent, 8);
  return (((c>>3)&1) ? v2[1] : v2[0]) + got;
}

// ---------------- ONE-SHOT prep: convert + all weight transposes (contiguous dst regions) ----------------
__global__ __launch_bounds__(256) void k_prep(const float* ele, const float* W_embed, const float* W_edge,
    const float* Wq, const float* Wk, const float* Wv, const float* Wr1, const float* Wo,
    const float* W1, const float* W2, const float* W_feat, const float* hW1, const float* hW2,
    const float* Wr2, u16* dst){
  int idx = blockIdx.x*256 + threadIdx.x;
  if(idx >= 411392) return;
  u16 v;
  if(idx < 3840){                    // ele convert
    v = f2bf(ele[idx]);
  } else if(idx < 5888){             // WembT: R=32,C=64,Rpad=32
    int l = idx - 3840;
    int cI = l >> 5, rI = l & 31;
    v = f2bf(W_embed[rI*64 + cI]);
  } else if(idx < 16128){            // WedgeT: R=137,C=64,Rpad=160
    int l = idx - 5888;
    int cI = l / 160, rI = l - cI*160;
    v = (rI < 137) ? f2bf(W_edge[rI*64 + cI]) : (u16)0;
  } else if(idx < 139008){           // Wq,Wk,Wv,Wr1,Wo: 5 x 6 x 64x64
    int l = idx - 16128;
    int which = l / 24576;
    int rem = l - which*24576;
    const float* src = (which==0)?Wq:(which==1)?Wk:(which==2)?Wv:(which==3)?Wr1:Wo;
    int b = rem >> 12;
    int r2 = rem & 4095;
    int cI = r2 >> 6, rI = r2 & 63;
    v = f2bf(src[b*4096 + rI*64 + cI]);
  } else if(idx < 237312){           // W1T: B=6,R=64,C=256,Rpad=64
    int l = idx - 139008;
    int b = l / 16384;
    int rem = l - b*16384;
    int cI = rem >> 6, rI = rem & 63;
    v = f2bf(W1[b*16384 + rI*256 + cI]);
  } else if(idx < 335616){           // W2T: B=6,R=256,C=64,Rpad=256
    int l = idx - 237312;
    int b = l / 16384;
    int rem = l - b*16384;
    int cI = rem >> 8, rI = rem & 255;
    v = f2bf(W2[b*16384 + rI*64 + cI]);
  } else if(idx < 368384){           // WfT: R=64,C=512,Rpad=64
    int l = idx - 335616;
    int cI = l >> 6, rI = l & 63;
    v = f2bf(W_feat[rI*512 + cI]);
  } else if(idx < 401152){           // hW1T: R=512,C=64,Rpad=512
    int l = idx - 368384;
    int cI = l >> 9, rI = l & 511;
    v = f2bf(hW1[rI*64 + cI]);
  } else if(idx < 405248){           // hW2T: R=64,C=64
    int l = idx - 401152;
    int cI = l >> 6, rI = l & 63;
    v = f2bf(hW2[rI*64 + cI]);
  } else {                           // Wr2T: 6 x [16 x 64] bf16, row n=head (pad 4->16), col k=hidden
    int l = idx - 405248;
    int b = l >> 10;
    int rem = l & 1023;
    int n = rem >> 6, k = rem & 63;
    v = (n < 4) ? f2bf(Wr2[b*256 + k*4 + n]) : (u16)0;
  }
  dst[idx] = v;
}

// ---------------- CSR build ----------------
__global__ __launch_bounds__(256) void k_count(const int* dstI, int* deg, int E){
  int tid = blockIdx.x*256 + threadIdx.x;
  if(tid < E) atomicAdd(&deg[dstI[tid]], 1);
}
__global__ __launch_bounds__(1024) void k_scan(const int* deg, int* rowptr, int* cursor, int N){
  __shared__ int wsum[17];
  int tid = threadIdx.x;
  int per = (N + 1023) >> 10;
  int base = tid * per;
  int s = 0;
  for(int i=0;i<per;i++){ int idx = base+i; if(idx < N) s += deg[idx]; }
  int lane = tid & 63, wid = tid >> 6;
  int inc = s;
  for(int d=1; d<64; d<<=1){
    int t = __shfl_up(inc, d);
    if(lane >= d) inc += t;
  }
  if(lane == 63) wsum[wid+1] = inc;
  if(tid == 0) wsum[0] = 0;
  __syncthreads();
  if(tid == 0){ for(int w=1; w<=16; w++) wsum[w] += wsum[w-1]; }
  __syncthreads();
  int run = inc - s + wsum[wid];
  for(int i=0;i<per;i++){
    int idx = base + i;
    if(idx < N){ rowptr[idx] = run; cursor[idx] = run; run += deg[idx]; }
  }
  if(tid == 1023) rowptr[N] = wsum[16];
}
__global__ __launch_bounds__(256) void k_scatter(const int* dstI, int* cursor, int* csr, int E){
  int tid = blockIdx.x*256 + threadIdx.x;
  if(tid < E){
    int p = atomicAdd(&cursor[dstI[tid]], 1);
    csr[p] = tid;
  }
}

// ---------------- e = [nf_src, nf_dst, sh, rbf] @ W_edge in CSR-PERMUTED order ----------------
__global__ __launch_bounds__(256) void k_edge_embed(const int* csr, const int* srcI, const int* dstI,
    const int* atom, const u16* ele, const float* evec, const u16* Bt,
    u16* ebf, float* r2, int* src2, int* dst2, int E){
  int wave = (blockIdx.x*blockDim.x + threadIdx.x) >> 6;
  int lane = threadIdx.x & 63;
  int row0 = wave*16; if(row0 >= E) return;
  int c = lane & 15, q = lane >> 4;
  int p = row0 + c;
  int e = csr[p];
  int sn = srcI[e], dn = dstI[e];
  float vx = evec[(size_t)e*3+0];
  float vy = evec[(size_t)e*3+1];
  float vz = evec[(size_t)e*3+2];
  float r = sqrtf(vx*vx + vy*vy + vz*vz);
  if(q == 0){ r2[p] = r; src2[p] = sn; dst2[p] = dn; }
  float inv = 1.f/(r + 1e-12f);
  // u = edge_vec[:, [1,2,0]] / r -> x=v1, y=v2, z=v0
  float x = vy*inv, y = vz*inv, z = vx*inv;
  const float s3 = 1.7320508075688772f, s15 = 3.872983346207417f;
  const float s5h = 1.118033988749895f, s15h = 1.9364916731037085f;
  float sh[9];
  sh[0] = 1.f; sh[1] = s3*x; sh[2] = s3*y; sh[3] = s3*z;
  sh[4] = s15*x*y; sh[5] = s15*y*z; sh[6] = s5h*(3.f*z*z - 1.f);
  sh[7] = s15*x*z; sh[8] = s15h*(x*x - y*y);
  s8v a[5];
  a[0] = *reinterpret_cast<const s8v*>(ele + (size_t)atom[sn]*32 + q*8);
  a[1] = *reinterpret_cast<const s8v*>(ele + (size_t)atom[dn]*32 + q*8);
  #pragma unroll
  for(int j=0;j<8;j++){
    int col = 64 + q*8 + j;
    u16 v;
    if(q == 0)            v = f2bf(sh[j]);
    else if(col < 73)     v = f2bf(sh[8]);
    else { float d = r - (10.f/63.f)*(float)(col-73); v = f2bf(__expf(-81.92f*d*d)); }
    a[2][j] = (short)v;
  }
  #pragma unroll
  for(int j=0;j<8;j++){
    float d = r - (10.f/63.f)*(float)(23 + q*8 + j);
    a[3][j] = (short)f2bf(__expf(-81.92f*d*d));
  }
  #pragma unroll
  for(int j=0;j<8;j++){
    int col = 128 + q*8 + j;
    u16 v = 0;
    if(col < 137){ float d = r - (10.f/63.f)*(float)(col-73); v = f2bf(__expf(-81.92f*d*d)); }
    a[4][j] = (short)v;
  }
  #pragma unroll
  for(int ct=0; ct<4; ct++){
    f32x4 acc = {0.f,0.f,0.f,0.f};
    #pragma unroll
    for(int kc=0; kc<5; kc++){
      s8v b = *reinterpret_cast<const s8v*>(Bt + (ct*16+c)*160 + kc*32 + q*8);
      acc = MFMA(a[kc], b, acc);
    }
    #pragma unroll
    for(int r_=0;r_<4;r_++) ebf[(size_t)(row0+q*4+r_)*64 + ct*16 + c] = f2bf(acc[r_]);
  }
}

// ---------------- one-shot: radial[l][e][h] via 2-stage MFMA with same-wave LDS roundtrip ----------------
__global__ __launch_bounds__(256) void k_radial6(const float* r2, const u16* Wr1T, const u16* Wr2T,
    float* rad6, int E){
  __shared__ u16 ldsS[4][16*72];
  int widL = threadIdx.x >> 6;
  int wave = (blockIdx.x*256 + threadIdx.x) >> 6;
  int lane = threadIdx.x & 63;
  int row0 = wave*16; if(row0 >= E) return;
  int c = lane & 15, q = lane >> 4;
  u16* LS = ldsS[widL];
  float re = r2[row0 + c];
  s8v r0, r1;
  #pragma unroll
  for(int j=0;j<8;j++){
    float d0 = re - (10.f/63.f)*(float)(q*8+j);
    float d1 = re - (10.f/63.f)*(float)(32+q*8+j);
    r0[j] = (short)f2bf(__expf(-81.92f*d0*d0));
    r1[j] = (short)f2bf(__expf(-81.92f*d1*d1));
  }
  for(int l=0; l<6; l++){
    const u16* W1l = Wr1T + l*4096;
    // stage 1: hid = rbf @ Wr1 (C layout); silu -> LDS bf16 (edge-row-major)
    #pragma unroll
    for(int ct=0; ct<4; ct++){
      s8v bw0 = *reinterpret_cast<const s8v*>(W1l + (ct*16+c)*64 + q*8);
      s8v bw1 = *reinterpret_cast<const s8v*>(W1l + (ct*16+c)*64 + 32 + q*8);
      f32x4 hacc = {0.f,0.f,0.f,0.f};
      hacc = MFMA(r0, bw0, hacc); hacc = MFMA(r1, bw1, hacc);
      #pragma unroll
      for(int r=0;r<4;r++){
        float y = hacc[r];
        LS[(q*4+r)*72 + ct*16 + c] = f2bf(y / (1.f + __expf(-y)));
      }
    }
    // stage 2 (same-wave LDS roundtrip, no barrier needed): radial = siluhid @ Wr2 (padded to 16 cols)
    s8v s0 = *reinterpret_cast<const s8v*>(LS + c*72 + q*8);
    s8v s1 = *reinterpret_cast<const s8v*>(LS + c*72 + 32 + q*8);
    const u16* W2l = Wr2T + l*1024;
    s8v b0 = *reinterpret_cast<const s8v*>(W2l + c*64 + q*8);
    s8v b1 = *reinterpret_cast<const s8v*>(W2l + c*64 + 32 + q*8);
    f32x4 acc = {0.f,0.f,0.f,0.f};
    acc = MFMA(s0, b0, acc);
    acc = MFMA(s1, b1, acc);
    if(c < 4){
      #pragma unroll
      for(int r=0;r<4;r++)
        rad6[(size_t)l*E*4 + (size_t)(row0+q*4+r)*4 + c] = acc[r];
    }
  }
}

// ---------------- pre: x = ele[atom]@Wemb; h0 = LN(x); Q0 = h0@Wq0 (Qt layout) ----------------
__global__ __launch_bounds__(256) void k_pre(const int* atom, const u16* ele, const u16* WembT,
    const u16* WqT0, float* xb, u16* hbf, float* Qt, int M){
  __shared__ u16 ldsH[4][16*72];
  int widL = threadIdx.x >> 6;
  int wave = (blockIdx.x*256 + threadIdx.x) >> 6;
  int lane = threadIdx.x & 63;
  int row0 = wave*16; if(row0 >= M) return;
  int c = lane & 15, q = lane >> 4;
  u16* LH = ldsH[widL];
  int at = atom[row0 + c];
  s8v a = *reinterpret_cast<const s8v*>(ele + (size_t)at*32 + q*8);
  float nx[4][4];
  #pragma unroll
  for(int ct=0; ct<4; ct++){
    s8v b = *reinterpret_cast<const s8v*>(WembT + (ct*16+c)*32 + q*8);
    f32x4 acc = {0.f,0.f,0.f,0.f};
    acc = MFMA(a, b, acc);
    #pragma unroll
    for(int r=0;r<4;r++){
      xb[(size_t)(row0+q*4+r)*64 + ct*16 + c] = acc[r];
      nx[ct][r] = acc[r];
    }
  }
  #pragma unroll
  for(int r=0;r<4;r++){
    float s = nx[0][r]+nx[1][r]+nx[2][r]+nx[3][r];
    QREDUCE16(s);
    float m = s*(1.f/64.f);
    float vv = 0.f;
    #pragma unroll
    for(int ct=0;ct<4;ct++){ float d = nx[ct][r]-m; vv += d*d; }
    QREDUCE16(vv);
    float rs = rsqrtf(vv*(1.f/64.f) + 1e-6f);
    #pragma unroll
    for(int ct=0;ct<4;ct++){
      u16 hb = f2bf((nx[ct][r]-m)*rs);
      hbf[(size_t)(row0+q*4+r)*64 + ct*16 + c] = hb;
      LH[(q*4+r)*72 + ct*16 + c] = hb;
    }
  }
  s8v h0 = *reinterpret_cast<const s8v*>(LH + c*72 + q*8);
  s8v h1 = *reinterpret_cast<const s8v*>(LH + c*72 + 32 + q*8);
  #pragma unroll
  for(int ct=0; ct<4; ct++){
    s8v b0 = *reinterpret_cast<const s8v*>(WqT0 + (ct*16+c)*64 + q*8);
    s8v b1 = *reinterpret_cast<const s8v*>(WqT0 + (ct*16+c)*64 + 32 + q*8);
    f32x4 acc = {0.f,0.f,0.f,0.f};
    acc = MFMA(h0, b0, acc);
    acc = MFMA(h1, b1, acc);
    #pragma unroll
    for(int r=0;r<4;r++) Qt[(size_t)(row0+q*4+r)*64 + c*4 + ct] = acc[r];
  }
}

// ---------------- fused k,v MFMAs + qk logits (butterfly) + radial table + exp ----------------
__global__ __launch_bounds__(256) void k_kvrad(const u16* hbf, const u16* ebf,
    const int* src2, const int* dst2, const float* Qt, const float* r2, const float* radial,
    const u16* WkT, const u16* WvT, u16* vbf, float* exb, int E){
  int wave = (blockIdx.x*256 + threadIdx.x) >> 6;
  int lane = threadIdx.x & 63;
  int row0 = wave*16;
  int c = lane & 15, q = lane >> 4;
  int sr = src2[row0 + c];
  s8v a0, a1;
  {
    s8v h0 = *reinterpret_cast<const s8v*>(hbf + (size_t)sr*64 + q*8);
    s8v h1 = *reinterpret_cast<const s8v*>(hbf + (size_t)sr*64 + 32 + q*8);
    s8v e0 = *reinterpret_cast<const s8v*>(ebf + (size_t)(row0+c)*64 + q*8);
    s8v e1 = *reinterpret_cast<const s8v*>(ebf + (size_t)(row0+c)*64 + 32 + q*8);
    #pragma unroll
    for(int j=0;j<8;j++){
      a0[j] = (short)f2bf(bf2f((u16)h0[j]) + bf2f((u16)e0[j]));
      a1[j] = (short)f2bf(bf2f((u16)h1[j]) + bf2f((u16)e1[j]));
    }
  }
  const float4* QtV = reinterpret_cast<const float4*>(Qt);
  float4 qv[4];
  #pragma unroll
  for(int r=0;r<4;r++){
    int dr = dst2[row0 + q*4 + r];
    qv[r] = QtV[(size_t)dr*16 + c];
  }
  float val[16];
  #pragma unroll
  for(int i=0;i<16;i++) val[i] = 0.f;
  #pragma unroll
  for(int ct=0; ct<4; ct++){
    s8v bk0 = *reinterpret_cast<const s8v*>(WkT + (ct*16+c)*64 + q*8);
    s8v bk1 = *reinterpret_cast<const s8v*>(WkT + (ct*16+c)*64 + 32 + q*8);
    s8v bv0 = *reinterpret_cast<const s8v*>(WvT + (ct*16+c)*64 + q*8);
    s8v bv1 = *reinterpret_cast<const s8v*>(WvT + (ct*16+c)*64 + 32 + q*8);
    f32x4 kacc = {0.f,0.f,0.f,0.f};
    kacc = MFMA(a0, bk0, kacc); kacc = MFMA(a1, bk1, kacc);
    f32x4 vacc = {0.f,0.f,0.f,0.f};
    vacc = MFMA(a0, bv0, vacc); vacc = MFMA(a1, bv1, vacc);
    #pragma unroll
    for(int r=0;r<4;r++){
      vbf[(size_t)row0*64 + (r*4+ct)*64 + q*16 + c] = f2bf(vacc[r]);
      float qc = (ct==0)?qv[r].x:(ct==1)?qv[r].y:(ct==2)?qv[r].z:qv[r].w;
      val[r*4+ct] += 0.25f * kacc[r] * qc;
    }
  }
  float qk = quad_butterfly16(val, c);   // lane c: (r=c>>2, h=c&3)
  float logit = qk + radial[(size_t)row0*4 + lane];
  int row = row0 + q*4 + (c>>2);
  exb[(size_t)row0*4 + lane] = (r2[row] < 10.f) ? __expf(logit) : 0.f;
}

// ---------------- softmax-denominator + aggregation; edges contiguous per node ----------------
__global__ __launch_bounds__(256) void k_agg(const int* rowptr, const float* exb, const u16* vbf, u16* aggbf, int N){
  int wave = (blockIdx.x*256 + threadIdx.x) >> 6;
  int lane = threadIdx.x & 63;
  if(wave >= N) return;
  int s0 = rowptr[wave], s1 = rowptr[wave+1];
  float s[4] = {0.f,0.f,0.f,0.f};
  for(int p = s0 + lane; p < s1; p += 64){
    float4 ev = *reinterpret_cast<const float4*>(exb + (size_t)p*4);
    s[0] += ev.x; s[1] += ev.y; s[2] += ev.z; s[3] += ev.w;
  }
  #pragma unroll
  for(int i=0;i<4;i++){ WREDUCE64(s[i]); }
  int ep = lane >> 4, cc = lane & 15;
  int hh = cc >> 2;
  int swz = hh*64 + (cc&3)*4;
  float inv = 1.f/(s[hh] + 1e-9f);
  float a0=0.f, a1=0.f, a2=0.f, a3=0.f;
  for(int p = s0 + ep; p < s1; p += 4){
    int t = p & 15;
    size_t base = (size_t)(p & ~15)*64 + (size_t)((t&3)*256) + (size_t)((t>>2)*16) + swz;
    ushort4 v4 = *reinterpret_cast<const ushort4*>(vbf + base);
    float ex = exb[(size_t)p*4 + hh];
    a0 += ex*bf2f(v4.x); a1 += ex*bf2f(v4.y); a2 += ex*bf2f(v4.z); a3 += ex*bf2f(v4.w);
  }
  a0 += __shfl_xor(a0,16); a0 += __shfl_xor(a0,32);
  a1 += __shfl_xor(a1,16); a1 += __shfl_xor(a1,32);
  a2 += __shfl_xor(a2,16); a2 += __shfl_xor(a2,32);
  a3 += __shfl_xor(a3,16); a3 += __shfl_xor(a3,32);
  if(ep == 0){
    ushort4 o;
    o.x = f2bf(a0*inv); o.y = f2bf(a1*inv); o.z = f2bf(a2*inv); o.w = f2bf(a3*inv);
    *reinterpret_cast<ushort4*>(aggbf + (size_t)wave*64 + cc*4) = o;
  }
}

// ---------------- MEGA: x+=agg@Wo; LN; FFN1; FFN2+residual; LN->hbf; Q_next->Qt ----------------
__global__ __launch_bounds__(256) void k_mega(const u16* aggbf, const u16* WoT, float* x,
    const u16* W1T, const u16* W2T, const u16* WqTn, float* Qt, u16* hbf, u16* xbf,
    int writex, int haveQ, int M){
  __shared__ u16 ldsH[4][16*72];
  __shared__ u16 ldsT[4][16*264];
  int widL = threadIdx.x >> 6;
  int wave = (blockIdx.x*256 + threadIdx.x) >> 6;
  int lane = threadIdx.x & 63;
  int row0 = wave*16; if(row0 >= M) return;
  int c = lane & 15, q = lane >> 4;
  u16* LH = ldsH[widL];
  u16* LT = ldsT[widL];
  {
    s8v a0 = *reinterpret_cast<const s8v*>(aggbf + (size_t)(row0+c)*64 + q*8);
    s8v a1 = *reinterpret_cast<const s8v*>(aggbf + (size_t)(row0+c)*64 + 32 + q*8);
    float nx[4][4];
    #pragma unroll
    for(int ct=0; ct<4; ct++){
      s8v b0 = *reinterpret_cast<const s8v*>(WoT + (ct*16+c)*64 + q*8);
      s8v b1 = *reinterpret_cast<const s8v*>(WoT + (ct*16+c)*64 + 32 + q*8);
      f32x4 acc = {0.f,0.f,0.f,0.f};
      acc = MFMA(a0, b0, acc);
      acc = MFMA(a1, b1, acc);
      #pragma unroll
      for(int r=0;r<4;r++){
        size_t idx = (size_t)(row0+q*4+r)*64 + ct*16 + c;
        float t = x[idx] + acc[r];
        x[idx] = t;
        nx[ct][r] = t;
      }
    }
    #pragma unroll
    for(int r=0;r<4;r++){
      float s = nx[0][r]+nx[1][r]+nx[2][r]+nx[3][r];
      QREDUCE16(s);
      float m = s*(1.f/64.f);
      float vv = 0.f;
      #pragma unroll
      for(int ct=0;ct<4;ct++){ float d = nx[ct][r]-m; vv += d*d; }
      QREDUCE16(vv);
      float rs = rsqrtf(vv*(1.f/64.f) + 1e-6f);
      #pragma unroll
      for(int ct=0;ct<4;ct++)
        LH[(q*4+r)*72 + ct*16 + c] = f2bf((nx[ct][r]-m)*rs);
    }
  }
  {
    s8v h0 = *reinterpret_cast<const s8v*>(LH + c*72 + q*8);
    s8v h1 = *reinterpret_cast<const s8v*>(LH + c*72 + 32 + q*8);
    #pragma unroll
    for(int ct=0; ct<16; ct++){
      s8v b0 = *reinterpret_cast<const s8v*>(W1T + (ct*16+c)*64 + q*8);
      s8v b1 = *reinterpret_cast<const s8v*>(W1T + (ct*16+c)*64 + 32 + q*8);
      f32x4 acc = {0.f,0.f,0.f,0.f};
      acc = MFMA(h0, b0, acc);
      acc = MFMA(h1, b1, acc);
      #pragma unroll
      for(int r=0;r<4;r++){
        float y = acc[r];
        LT[(q*4+r)*264 + ct*16 + c] = f2bf(y / (1.f + __expf(-y)));
      }
    }
  }
  {
    s8v a[8];
    #pragma unroll
    for(int kc=0; kc<8; kc++)
      a[kc] = *reinterpret_cast<const s8v*>(LT + c*264 + kc*32 + q*8);
    float nx[4][4];
    #pragma unroll
    for(int ct=0; ct<4; ct++){
      f32x4 acc = {0.f,0.f,0.f,0.f};
      #pragma unroll
      for(int kc=0; kc<8; kc++){
        s8v b = *reinterpret_cast<const s8v*>(W2T + (ct*16+c)*256 + kc*32 + q*8);
        acc = MFMA(a[kc], b, acc);
      }
      #pragma unroll
      for(int r=0;r<4;r++){
        size_t idx = (size_t)(row0+q*4+r)*64 + ct*16 + c;
        float t = x[idx] + acc[r];
        x[idx] = t;
        nx[ct][r] = t;
        if(writex) xbf[idx] = f2bf(t);
      }
    }
    #pragma unroll
    for(int r=0;r<4;r++){
      float s = nx[0][r]+nx[1][r]+nx[2][r]+nx[3][r];
      QREDUCE16(s);
      float m = s*(1.f/64.f);
      float vv = 0.f;
      #pragma unroll
      for(int ct=0;ct<4;ct++){ float d = nx[ct][r]-m; vv += d*d; }
      QREDUCE16(vv);
      float rs = rsqrtf(vv*(1.f/64.f) + 1e-6f);
      #pragma unroll
      for(int ct=0;ct<4;ct++){
        u16 hb = f2bf((nx[ct][r]-m)*rs);
        hbf[(size_t)(row0+q*4+r)*64 + ct*16 + c] = hb;
        LH[(q*4+r)*72 + ct*16 + c] = hb;
      }
    }
  }
  if(haveQ){
    s8v h0 = *reinterpret_cast<const s8v*>(LH + c*72 + q*8);
    s8v h1 = *reinterpret_cast<const s8v*>(LH + c*72 + 32 + q*8);
    #pragma unroll
    for(int ct=0; ct<4; ct++){
      s8v b0 = *reinterpret_cast<const s8v*>(WqTn + (ct*16+c)*64 + q*8);
      s8v b1 = *reinterpret_cast<const s8v*>(WqTn + (ct*16+c)*64 + 32 + q*8);
      f32x4 acc = {0.f,0.f,0.f,0.f};
      acc = MFMA(h0, b0, acc);
      acc = MFMA(h1, b1, acc);
      #pragma unroll
      for(int r=0;r<4;r++) Qt[(size_t)(row0+q*4+r)*64 + c*4 + ct] = acc[r];
    }
  }
}

// ---------------- feat = x @ W_feat with in-register LN over 512 -> featbf ----------------
__global__ __launch_bounds__(256) void k_feat_ln(const u16* A, const u16* Bt, u16* out, int M){
  int wave = (blockIdx.x*256 + threadIdx.x) >> 6;
  int lane = threadIdx.x & 63;
  int row0 = wave*16; if(row0 >= M) return;
  int c = lane & 15, q = lane >> 4;
  s8v a0 = *reinterpret_cast<const s8v*>(A + (size_t)(row0+c)*64 + q*8);
  s8v a1 = *reinterpret_cast<const s8v*>(A + (size_t)(row0+c)*64 + 32 + q*8);
  float fa[32][4];
  #pragma unroll
  for(int ct=0; ct<32; ct++){
    s8v b0 = *reinterpret_cast<const s8v*>(Bt + (ct*16+c)*64 + q*8);
    s8v b1 = *reinterpret_cast<const s8v*>(Bt + (ct*16+c)*64 + 32 + q*8);
    f32x4 acc = {0.f,0.f,0.f,0.f};
    acc = MFMA(a0, b0, acc);
    acc = MFMA(a1, b1, acc);
    #pragma unroll
    for(int r=0;r<4;r++) fa[ct][r] = acc[r];
  }
  #pragma unroll
  for(int r=0;r<4;r++){
    float s = 0.f;
    #pragma unroll
    for(int ct=0;ct<32;ct++) s += fa[ct][r];
    QREDUCE16(s);
    float m = s*(1.f/512.f);
    float vv = 0.f;
    #pragma unroll
    for(int ct=0;ct<32;ct++){ float d = fa[ct][r]-m; vv += d*d; }
    QREDUCE16(vv);
    float rs = rsqrtf(vv*(1.f/512.f) + 1e-6f);
    #pragma unroll
    for(int ct=0;ct<32;ct++)
      out[(size_t)(row0+q*4+r)*512 + ct*16 + c] = f2bf((fa[ct][r]-m)*rs);
  }
}

// ---------------- head1 (K=512) + bias + LN + relu -> hh1 ----------------
__global__ __launch_bounds__(256) void k_head1_ln(const u16* A, const u16* Bt, const float* hb, u16* out, int M){
  int wave = (blockIdx.x*256 + threadIdx.x) >> 6;
  int lane = threadIdx.x & 63;
  int row0 = wave*16; if(row0 >= M) return;
  int c = lane & 15, q = lane >> 4;
  s8v a[16];
  #pragma unroll
  for(int kc=0; kc<16; kc++)
    a[kc] = *reinterpret_cast<const s8v*>(A + (size_t)(row0+c)*512 + kc*32 + q*8);
  float y[4][4];
  #pragma unroll
  for(int ct=0; ct<4; ct++){
    f32x4 acc = {0.f,0.f,0.f,0.f};
    #pragma unroll
    for(int kc=0; kc<16; kc++){
      s8v b = *reinterpret_cast<const s8v*>(Bt + (size_t)(ct*16+c)*512 + kc*32 + q*8);
      acc = MFMA(a[kc], b, acc);
    }
    float bi = hb[ct*16+c];
    #pragma unroll
    for(int r=0;r<4;r++) y[ct][r] = acc[r] + bi;
  }
  #pragma unroll
  for(int r=0;r<4;r++){
    float s = y[0][r]+y[1][r]+y[2][r]+y[3][r];
    QREDUCE16(s);
    float m = s*(1.f/64.f);
    float vv = 0.f;
    #pragma unroll
    for(int ct=0;ct<4;ct++){ float d = y[ct][r]-m; vv += d*d; }
    QREDUCE16(vv);
    float rs = rsqrtf(vv*(1.f/64.f) + 1e-6f);
    #pragma unroll
    for(int ct=0;ct<4;ct++)
      out[(size_t)(row0+q*4+r)*64 + ct*16 + c] = f2bf(fmaxf((y[ct][r]-m)*rs, 0.f));
  }
}

// ---------------- head2 + bias + LN + relu + dot(hW3) + pooled atomicAdd ----------------
__global__ __launch_bounds__(256) void k_head2_energy(const u16* A, const u16* Bt, const float* hb,
    const float* hW3, const float* hb3, const int* batch, float* pooled, int M){
  int wave = (blockIdx.x*256 + threadIdx.x) >> 6;
  int lane = threadIdx.x & 63;
  int row0 = wave*16; if(row0 >= M) return;
  int c = lane & 15, q = lane >> 4;
  s8v a0 = *reinterpret_cast<const s8v*>(A + (size_t)(row0+c)*64 + q*8);
  s8v a1 = *reinterpret_cast<const s8v*>(A + (size_t)(row0+c)*64 + 32 + q*8);
  float y[4][4];
  #pragma unroll
  for(int ct=0; ct<4; ct++){
    s8v b0 = *reinterpret_cast<const s8v*>(Bt + (ct*16+c)*64 + q*8);
    s8v b1 = *reinterpret_cast<const s8v*>(Bt + (ct*16+c)*64 + 32 + q*8);
    f32x4 acc = {0.f,0.f,0.f,0.f};
    acc = MFMA(a0, b0, acc);
    acc = MFMA(a1, b1, acc);
    float bi = hb[ct*16+c];
    #pragma unroll
    for(int r=0;r<4;r++) y[ct][r] = acc[r] + bi;
  }
  float w3[4];
  #pragma unroll
  for(int ct=0;ct<4;ct++) w3[ct] = hW3[ct*16+c];
  float ep[4];
  #pragma unroll
  for(int r=0;r<4;r++){
    float s = y[0][r]+y[1][r]+y[2][r]+y[3][r];
    QREDUCE16(s);
    float m = s*(1.f/64.f);
    float vv = 0.f;
    #pragma unroll
    for(int ct=0;ct<4;ct++){ float d = y[ct][r]-m; vv += d*d; }
    QREDUCE16(vv);
    float rs = rsqrtf(vv*(1.f/64.f) + 1e-6f);
    float e = 0.f;
    #pragma unroll
    for(int ct=0;ct<4;ct++) e += fmaxf((y[ct][r]-m)*rs, 0.f) * w3[ct];
    QREDUCE16(e);
    ep[r] = e;
  }
  if(c < 4){
    float ev = (c==0)?ep[0]:(c==1)?ep[1]:(c==2)?ep[2]:ep[3];
    int row = row0 + q*4 + c;
    atomicAdd(&pooled[batch[row]], ev + hb3[0]);
  }
}

// ---------------- output f32 ----------------
__global__ __launch_bounds__(256) void k_out(const float* pooled, float* out, int G){
  int tid = blockIdx.x*256 + threadIdx.x;
  if(tid < G) out[tid] = pooled[tid] * 0.11785113019775793f; // 1/sqrt(72)
}

extern "C" void kernel_launch(void* const* d_in, const int* in_sizes, int n_in,
                              void* d_out, int out_size, void* d_ws, size_t ws_size,
                              hipStream_t stream){
  const int*   edge_src  = (const int*)d_in[1];
  const int*   edge_dst  = (const int*)d_in[2];
  const float* edge_vec  = (const float*)d_in[3];
  const int*   batch     = (const int*)d_in[4];
  const int*   node_atom = (const int*)d_in[5];
  const float* ele    = (const float*)d_in[6];
  const float* W_embed= (const float*)d_in[7];
  const float* W_edge = (const float*)d_in[8];
  const float* Wq = (const float*)d_in[9];
  const float* Wk = (const float*)d_in[10];
  const float* Wv = (const float*)d_in[11];
  const float* Wr1= (const float*)d_in[12];
  const float* Wr2= (const float*)d_in[13];
  const float* Wo = (const float*)d_in[14];
  const float* W1 = (const float*)d_in[15];
  const float* W2 = (const float*)d_in[16];
  const float* W_feat=(const float*)d_in[17];
  const float* hW1= (const float*)d_in[18];
  const float* hb1= (const float*)d_in[19];
  const float* hW2= (const float*)d_in[20];
  const float* hb2= (const float*)d_in[21];
  const float* hW3= (const float*)d_in[22];
  const float* hb3= (const float*)d_in[23];
  (void)n_in; (void)ws_size;

  const int E = in_sizes[1];
  const int N = in_sizes[4];
  const int G = out_size;

  // ---- workspace layout: peak ~113 MB ----
  char* base = (char*)d_ws;
  size_t off = 0;
  #define ALLOC(ty, name, count) ty* name = (ty*)(base + off); off = (off + (size_t)(count)*sizeof(ty) + 255) & ~(size_t)255;
  ALLOC(float, r2,    E)
  ALLOC(int,   src2,  E)
  ALLOC(int,   dst2,  E)
  ALLOC(u16,   ebf,   (size_t)E*64)
  ALLOC(u16,   vbf,   (size_t)E*64)
  ALLOC(float, exb,   (size_t)E*4)
  ALLOC(float, rad6,  (size_t)E*4*6)
  ALLOC(u16,   hbf,   (size_t)N*64)
  ALLOC(u16,   aggbf, (size_t)N*64)
  ALLOC(u16,   xbf,   (size_t)N*64)
  ALLOC(float, Qt,    (size_t)N*64)
  ALLOC(float, xb,    (size_t)N*64)
  ALLOC(int,   deg,   N)
  ALLOC(int,   rowptr,N+1)
  ALLOC(int,   cursor,N)
  ALLOC(int,   csr,   E)
  ALLOC(float, pooled,G)
  // contiguous prep-region (all counts x2 bytes are 256-multiples; no gaps)
  ALLOC(u16, ele_bf, 120*32)        // [0,3840)
  ALLOC(u16, WembT, 64*32)          // [3840,5888)
  ALLOC(u16, WedgeT,64*160)         // [5888,16128)
  ALLOC(u16, WqT,  6*64*64)         // [16128, ...)
  ALLOC(u16, WkT,  6*64*64)
  ALLOC(u16, WvT,  6*64*64)
  ALLOC(u16, Wr1T, 6*64*64)
  ALLOC(u16, WoT,  6*64*64)
  ALLOC(u16, W1T,  6*256*64)
  ALLOC(u16, W2T,  6*64*256)
  ALLOC(u16, WfT,  512*64)
  ALLOC(u16, hW1T, 64*512)
  ALLOC(u16, hW2T, 64*64)
  ALLOC(u16, Wr2T, 6*16*64)
  #undef ALLOC
  // tail aliases into loop-dead regions:
  u16* featbf = ebf;          // 16 MB <= 32 MB
  u16* hh1    = (u16*)exb;    // 2 MB <= 4 MB

  auto cdiv = [](int a, int b){ return (a + b - 1)/b; };

  k_prep<<<cdiv(411392,256),256,0,stream>>>(ele, W_embed, W_edge, Wq, Wk, Wv, Wr1, Wo,
                                            W1, W2, W_feat, hW1, hW2, Wr2, ele_bf);

  hipMemsetAsync(deg, 0, (size_t)N*sizeof(int), stream);
  hipMemsetAsync(pooled, 0, (size_t)G*sizeof(float), stream);

  k_count<<<cdiv(E,256),256,0,stream>>>(edge_dst, deg, E);
  k_scan<<<1,1024,0,stream>>>(deg, rowptr, cursor, N);
  k_scatter<<<cdiv(E,256),256,0,stream>>>(edge_dst, cursor, csr, E);
  k_edge_embed<<<E/64, 256, 0, stream>>>(csr, edge_src, edge_dst, node_atom, ele_bf, edge_vec,
                                         WedgeT, ebf, r2, src2, dst2, E);
  k_radial6<<<E/64,256,0,stream>>>(r2, Wr1T, Wr2T, rad6, E);
  k_pre<<<N/64,256,0,stream>>>(node_atom, ele_bf, WembT, WqT, xb, hbf, Qt, N);

  for(int l=0; l<6; l++){
    k_kvrad<<<E/64,256,0,stream>>>(hbf, ebf, src2, dst2, Qt, r2, rad6 + (size_t)l*E*4,
                                   WkT + l*4096, WvT + l*4096, vbf, exb, E);
    k_agg<<<cdiv(N,4),256,0,stream>>>(rowptr, exb, vbf, aggbf, N);
    k_mega<<<N/64,256,0,stream>>>(aggbf, WoT + l*4096, xb,
                                  W1T + l*16384, W2T + l*16384,
                                  WqT + ((l<5)?(l+1):0)*4096, Qt, hbf, xbf,
                                  (l==5)?1:0, (l<5)?1:0, N);
  }

  k_feat_ln<<<N/64,256,0,stream>>>(xbf, WfT, featbf, N);
  k_head1_ln<<<N/64,256,0,stream>>>(featbf, hW1T, hb1, hh1, N);
  k_head2_energy<<<N/64,256,0,stream>>>(hh1, hW2T, hb2, hW3, hb3, batch, pooled, N);
  k_out<<<cdiv(G,256),256,0,stream>>>(pooled, (float*)d_out, G);
}

// Round 15
// 748.731 us; speedup vs baseline: 1.1032x; 1.1032x over previous
//
#include <hip/hip_runtime.h>

typedef short s8v __attribute__((ext_vector_type(8)));
typedef float f32x4 __attribute__((ext_vector_type(4)));
typedef unsigned short u16;

__device__ __forceinline__ float bf2f(u16 h){
  union { unsigned u; float f; } v; v.u = ((unsigned)h) << 16; return v.f;
}
__device__ __forceinline__ u16 f2bf(float f){
  union { float f; unsigned u; } v; v.f = f;
  unsigned u = v.u;
  return (u16)((u + 0x7fffu + ((u >> 16) & 1u)) >> 16);
}
#define MFMA(a,b,c) __builtin_amdgcn_mfma_f32_16x16x32_bf16((a),(b),(c),0,0,0)

#define WREDUCE64(s) { s += __shfl_xor(s,1); s += __shfl_xor(s,2); s += __shfl_xor(s,4); \
                       s += __shfl_xor(s,8); s += __shfl_xor(s,16); s += __shfl_xor(s,32); }
#define QREDUCE16(s) { s += __shfl_xor(s,1); s += __shfl_xor(s,2); s += __shfl_xor(s,4); s += __shfl_xor(s,8); }

// 16-value butterfly within 16-lane quads: lane c (0..15) ends with sum-over-quad of val[c]
__device__ __forceinline__ float quad_butterfly16(float* val, int c){
  float v8[8], v4[4], v2[2];
  #pragma unroll
  for(int t=0;t<8;t++){
    float sent = (c&1) ? val[2*t] : val[2*t+1];
    float got = __shfl_xor(sent, 1);
    v8[t] = ((c&1) ? val[2*t+1] : val[2*t]) + got;
  }
  #pragma unroll
  for(int t=0;t<4;t++){
    float sent = ((c>>1)&1) ? v8[2*t] : v8[2*t+1];
    float got = __shfl_xor(sent, 2);
    v4[t] = (((c>>1)&1) ? v8[2*t+1] : v8[2*t]) + got;
  }
  #pragma unroll
  for(int t=0;t<2;t++){
    float sent = ((c>>2)&1) ? v4[2*t] : v4[2*t+1];
    float got = __shfl_xor(sent, 4);
    v2[t] = (((c>>2)&1) ? v4[2*t+1] : v4[2*t]) + got;
  }
  float sent = ((c>>3)&1) ? v2[0] : v2[1];
  float got = __shfl_xor(sent, 8);
  return (((c>>3)&1) ? v2[1] : v2[0]) + got;
}

// ---------------- ONE-SHOT prep: convert + all weight transposes (contiguous dst regions) ----------------
__global__ __launch_bounds__(256) void k_prep(const float* ele, const float* W_embed, const float* W_edge,
    const float* Wq, const float* Wk, const float* Wv, const float* Wr1, const float* Wo,
    const float* W1, const float* W2, const float* W_feat, const float* hW1, const float* hW2,
    u16* dst){
  int idx = blockIdx.x*256 + threadIdx.x;
  if(idx >= 405248) return;
  u16 v;
  if(idx < 3840){                    // ele convert
    v = f2bf(ele[idx]);
  } else if(idx < 5888){             // WembT: R=32,C=64,Rpad=32
    int l = idx - 3840;
    int cI = l >> 5, rI = l & 31;
    v = f2bf(W_embed[rI*64 + cI]);
  } else if(idx < 16128){            // WedgeT: R=137,C=64,Rpad=160
    int l = idx - 5888;
    int cI = l / 160, rI = l - cI*160;
    v = (rI < 137) ? f2bf(W_edge[rI*64 + cI]) : (u16)0;
  } else if(idx < 139008){           // Wq,Wk,Wv,Wr1,Wo: 5 x 6 x 64x64
    int l = idx - 16128;
    int which = l / 24576;
    int rem = l - which*24576;
    const float* src = (which==0)?Wq:(which==1)?Wk:(which==2)?Wv:(which==3)?Wr1:Wo;
    int b = rem >> 12;
    int r2 = rem & 4095;
    int cI = r2 >> 6, rI = r2 & 63;
    v = f2bf(src[b*4096 + rI*64 + cI]);
  } else if(idx < 237312){           // W1T: B=6,R=64,C=256,Rpad=64
    int l = idx - 139008;
    int b = l / 16384;
    int rem = l - b*16384;
    int cI = rem >> 6, rI = rem & 63;
    v = f2bf(W1[b*16384 + rI*256 + cI]);
  } else if(idx < 335616){           // W2T: B=6,R=256,C=64,Rpad=256
    int l = idx - 237312;
    int b = l / 16384;
    int rem = l - b*16384;
    int cI = rem >> 8, rI = rem & 255;
    v = f2bf(W2[b*16384 + rI*64 + cI]);
  } else if(idx < 368384){           // WfT: R=64,C=512,Rpad=64
    int l = idx - 335616;
    int cI = l >> 6, rI = l & 63;
    v = f2bf(W_feat[rI*512 + cI]);
  } else if(idx < 401152){           // hW1T: R=512,C=64,Rpad=512
    int l = idx - 368384;
    int cI = l >> 9, rI = l & 511;
    v = f2bf(hW1[rI*64 + cI]);
  } else {                           // hW2T: R=64,C=64
    int l = idx - 401152;
    int cI = l >> 6, rI = l & 63;
    v = f2bf(hW2[rI*64 + cI]);
  }
  dst[idx] = v;
}

// ---------------- CSR build ----------------
__global__ __launch_bounds__(256) void k_count(const int* dstI, int* deg, int E){
  int tid = blockIdx.x*256 + threadIdx.x;
  if(tid < E) atomicAdd(&deg[dstI[tid]], 1);
}
__global__ __launch_bounds__(1024) void k_scan(const int* deg, int* rowptr, int* cursor, int N){
  __shared__ int wsum[17];
  int tid = threadIdx.x;
  int per = (N + 1023) >> 10;
  int base = tid * per;
  int s = 0;
  for(int i=0;i<per;i++){ int idx = base+i; if(idx < N) s += deg[idx]; }
  int lane = tid & 63, wid = tid >> 6;
  int inc = s;
  for(int d=1; d<64; d<<=1){
    int t = __shfl_up(inc, d);
    if(lane >= d) inc += t;
  }
  if(lane == 63) wsum[wid+1] = inc;
  if(tid == 0) wsum[0] = 0;
  __syncthreads();
  if(tid == 0){ for(int w=1; w<=16; w++) wsum[w] += wsum[w-1]; }
  __syncthreads();
  int run = inc - s + wsum[wid];
  for(int i=0;i<per;i++){
    int idx = base + i;
    if(idx < N){ rowptr[idx] = run; cursor[idx] = run; run += deg[idx]; }
  }
  if(tid == 1023) rowptr[N] = wsum[16];
}
__global__ __launch_bounds__(256) void k_scatter(const int* dstI, int* cursor, int* csr, int E){
  int tid = blockIdx.x*256 + threadIdx.x;
  if(tid < E){
    int p = atomicAdd(&cursor[dstI[tid]], 1);
    csr[p] = tid;
  }
}

// ---------------- e = [nf_src, nf_dst, sh, rbf] @ W_edge in CSR-PERMUTED order ----------------
__global__ __launch_bounds__(256) void k_edge_embed(const int* csr, const int* srcI, const int* dstI,
    const int* atom, const u16* ele, const float* evec, const u16* Bt,
    u16* ebf, float* r2, int* src2, int* dst2, int E){
  int wave = (blockIdx.x*blockDim.x + threadIdx.x) >> 6;
  int lane = threadIdx.x & 63;
  int row0 = wave*16; if(row0 >= E) return;
  int c = lane & 15, q = lane >> 4;
  int p = row0 + c;
  int e = csr[p];
  int sn = srcI[e], dn = dstI[e];
  float vx = evec[(size_t)e*3+0];
  float vy = evec[(size_t)e*3+1];
  float vz = evec[(size_t)e*3+2];
  float r = sqrtf(vx*vx + vy*vy + vz*vz);
  if(q == 0){ r2[p] = r; src2[p] = sn; dst2[p] = dn; }
  float inv = 1.f/(r + 1e-12f);
  // u = edge_vec[:, [1,2,0]] / r -> x=v1, y=v2, z=v0
  float x = vy*inv, y = vz*inv, z = vx*inv;
  const float s3 = 1.7320508075688772f, s15 = 3.872983346207417f;
  const float s5h = 1.118033988749895f, s15h = 1.9364916731037085f;
  float sh[9];
  sh[0] = 1.f; sh[1] = s3*x; sh[2] = s3*y; sh[3] = s3*z;
  sh[4] = s15*x*y; sh[5] = s15*y*z; sh[6] = s5h*(3.f*z*z - 1.f);
  sh[7] = s15*x*z; sh[8] = s15h*(x*x - y*y);
  s8v a[5];
  a[0] = *reinterpret_cast<const s8v*>(ele + (size_t)atom[sn]*32 + q*8);
  a[1] = *reinterpret_cast<const s8v*>(ele + (size_t)atom[dn]*32 + q*8);
  #pragma unroll
  for(int j=0;j<8;j++){
    int col = 64 + q*8 + j;
    u16 v;
    if(q == 0)            v = f2bf(sh[j]);
    else if(col < 73)     v = f2bf(sh[8]);
    else { float d = r - (10.f/63.f)*(float)(col-73); v = f2bf(__expf(-81.92f*d*d)); }
    a[2][j] = (short)v;
  }
  #pragma unroll
  for(int j=0;j<8;j++){
    float d = r - (10.f/63.f)*(float)(23 + q*8 + j);
    a[3][j] = (short)f2bf(__expf(-81.92f*d*d));
  }
  #pragma unroll
  for(int j=0;j<8;j++){
    int col = 128 + q*8 + j;
    u16 v = 0;
    if(col < 137){ float d = r - (10.f/63.f)*(float)(col-73); v = f2bf(__expf(-81.92f*d*d)); }
    a[4][j] = (short)v;
  }
  #pragma unroll
  for(int ct=0; ct<4; ct++){
    f32x4 acc = {0.f,0.f,0.f,0.f};
    #pragma unroll
    for(int kc=0; kc<5; kc++){
      s8v b = *reinterpret_cast<const s8v*>(Bt + (ct*16+c)*160 + kc*32 + q*8);
      acc = MFMA(a[kc], b, acc);
    }
    #pragma unroll
    for(int r_=0;r_<4;r_++) ebf[(size_t)(row0+q*4+r_)*64 + ct*16 + c] = f2bf(acc[r_]);
  }
}

// ---------------- one-shot: radial TABLE over r-grid [0,10], 4096 intervals, all 6 layers ----------------
// radtab[l][i][h], i in [0,4096]; grid rows padded to 4112
#define RG 4096
#define RGROWS 4112
__global__ __launch_bounds__(256) void k_radtab(const u16* Wr1T, const float* Wr2, float* radtab){
  int wave = (blockIdx.x*256 + threadIdx.x) >> 6;
  int lane = threadIdx.x & 63;
  int row0 = wave*16; if(row0 >= RGROWS) return;
  int c = lane & 15, q = lane >> 4;
  float re = (10.f/RG)*(float)(row0 + c);
  s8v r0, r1;
  #pragma unroll
  for(int j=0;j<8;j++){
    float d0 = re - (10.f/63.f)*(float)(q*8+j);
    float d1 = re - (10.f/63.f)*(float)(32+q*8+j);
    r0[j] = (short)f2bf(__expf(-81.92f*d0*d0));
    r1[j] = (short)f2bf(__expf(-81.92f*d1*d1));
  }
  for(int l=0; l<6; l++){
    const u16* W1l = Wr1T + l*4096;
    const float4* wr2v = reinterpret_cast<const float4*>(Wr2 + l*256);
    float val[16];
    #pragma unroll
    for(int i=0;i<16;i++) val[i] = 0.f;
    #pragma unroll
    for(int ct=0; ct<4; ct++){
      s8v bw0 = *reinterpret_cast<const s8v*>(W1l + (ct*16+c)*64 + q*8);
      s8v bw1 = *reinterpret_cast<const s8v*>(W1l + (ct*16+c)*64 + 32 + q*8);
      f32x4 hacc = {0.f,0.f,0.f,0.f};
      hacc = MFMA(r0, bw0, hacc); hacc = MFMA(r1, bw1, hacc);
      float4 w2 = wr2v[ct*16 + c];
      #pragma unroll
      for(int r=0;r<4;r++){
        float y = hacc[r];
        float sv = y / (1.f + __expf(-y));
        val[r*4+0] += sv * w2.x;
        val[r*4+1] += sv * w2.y;
        val[r*4+2] += sv * w2.z;
        val[r*4+3] += sv * w2.w;
      }
    }
    float fin = quad_butterfly16(val, c);
    int row = row0 + q*4 + (c>>2);
    if(row <= RG)
      radtab[(size_t)l*RGROWS*4 + (size_t)row0*4 + lane] = fin;
  }
}

// ---------------- pre: x = ele[atom]@Wemb; h0 = LN(x); Q0 = h0@Wq0 (Qt layout) ----------------
__global__ __launch_bounds__(256) void k_pre(const int* atom, const u16* ele, const u16* WembT,
    const u16* WqT0, float* xb, u16* hbf, float* Qt, int M){
  __shared__ u16 ldsH[4][16*72];
  int widL = threadIdx.x >> 6;
  int wave = (blockIdx.x*256 + threadIdx.x) >> 6;
  int lane = threadIdx.x & 63;
  int row0 = wave*16; if(row0 >= M) return;
  int c = lane & 15, q = lane >> 4;
  u16* LH = ldsH[widL];
  int at = atom[row0 + c];
  s8v a = *reinterpret_cast<const s8v*>(ele + (size_t)at*32 + q*8);
  float nx[4][4];
  #pragma unroll
  for(int ct=0; ct<4; ct++){
    s8v b = *reinterpret_cast<const s8v*>(WembT + (ct*16+c)*32 + q*8);
    f32x4 acc = {0.f,0.f,0.f,0.f};
    acc = MFMA(a, b, acc);
    #pragma unroll
    for(int r=0;r<4;r++){
      xb[(size_t)(row0+q*4+r)*64 + ct*16 + c] = acc[r];
      nx[ct][r] = acc[r];
    }
  }
  #pragma unroll
  for(int r=0;r<4;r++){
    float s = nx[0][r]+nx[1][r]+nx[2][r]+nx[3][r];
    QREDUCE16(s);
    float m = s*(1.f/64.f);
    float vv = 0.f;
    #pragma unroll
    for(int ct=0;ct<4;ct++){ float d = nx[ct][r]-m; vv += d*d; }
    QREDUCE16(vv);
    float rs = rsqrtf(vv*(1.f/64.f) + 1e-6f);
    #pragma unroll
    for(int ct=0;ct<4;ct++){
      u16 hb = f2bf((nx[ct][r]-m)*rs);
      hbf[(size_t)(row0+q*4+r)*64 + ct*16 + c] = hb;
      LH[(q*4+r)*72 + ct*16 + c] = hb;
    }
  }
  s8v h0 = *reinterpret_cast<const s8v*>(LH + c*72 + q*8);
  s8v h1 = *reinterpret_cast<const s8v*>(LH + c*72 + 32 + q*8);
  #pragma unroll
  for(int ct=0; ct<4; ct++){
    s8v b0 = *reinterpret_cast<const s8v*>(WqT0 + (ct*16+c)*64 + q*8);
    s8v b1 = *reinterpret_cast<const s8v*>(WqT0 + (ct*16+c)*64 + 32 + q*8);
    f32x4 acc = {0.f,0.f,0.f,0.f};
    acc = MFMA(h0, b0, acc);
    acc = MFMA(h1, b1, acc);
    #pragma unroll
    for(int r=0;r<4;r++) Qt[(size_t)(row0+q*4+r)*64 + c*4 + ct] = acc[r];
  }
}

// ---------------- fused k,v MFMAs + qk logits (butterfly) + radial lerp + exp ----------------
__global__ __launch_bounds__(256) void k_kvrad(const u16* hbf, const u16* ebf,
    const int* src2, const int* dst2, const float* Qt, const float* r2, const float* radtab,
    const u16* WkT, const u16* WvT, u16* vbf, float* exb, int E){
  int wave = (blockIdx.x*256 + threadIdx.x) >> 6;
  int lane = threadIdx.x & 63;
  int row0 = wave*16;
  int c = lane & 15, q = lane >> 4;
  int sr = src2[row0 + c];
  s8v a0, a1;
  {
    s8v h0 = *reinterpret_cast<const s8v*>(hbf + (size_t)sr*64 + q*8);
    s8v h1 = *reinterpret_cast<const s8v*>(hbf + (size_t)sr*64 + 32 + q*8);
    s8v e0 = *reinterpret_cast<const s8v*>(ebf + (size_t)(row0+c)*64 + q*8);
    s8v e1 = *reinterpret_cast<const s8v*>(ebf + (size_t)(row0+c)*64 + 32 + q*8);
    #pragma unroll
    for(int j=0;j<8;j++){
      a0[j] = (short)f2bf(bf2f((u16)h0[j]) + bf2f((u16)e0[j]));
      a1[j] = (short)f2bf(bf2f((u16)h1[j]) + bf2f((u16)e1[j]));
    }
  }
  const float4* QtV = reinterpret_cast<const float4*>(Qt);
  float4 qv[4];
  #pragma unroll
  for(int r=0;r<4;r++){
    int dr = dst2[row0 + q*4 + r];
    qv[r] = QtV[(size_t)dr*16 + c];
  }
  float val[16];
  #pragma unroll
  for(int i=0;i<16;i++) val[i] = 0.f;
  #pragma unroll
  for(int ct=0; ct<4; ct++){
    s8v bk0 = *reinterpret_cast<const s8v*>(WkT + (ct*16+c)*64 + q*8);
    s8v bk1 = *reinterpret_cast<const s8v*>(WkT + (ct*16+c)*64 + 32 + q*8);
    s8v bv0 = *reinterpret_cast<const s8v*>(WvT + (ct*16+c)*64 + q*8);
    s8v bv1 = *reinterpret_cast<const s8v*>(WvT + (ct*16+c)*64 + 32 + q*8);
    f32x4 kacc = {0.f,0.f,0.f,0.f};
    kacc = MFMA(a0, bk0, kacc); kacc = MFMA(a1, bk1, kacc);
    f32x4 vacc = {0.f,0.f,0.f,0.f};
    vacc = MFMA(a0, bv0, vacc); vacc = MFMA(a1, bv1, vacc);
    #pragma unroll
    for(int r=0;r<4;r++){
      vbf[(size_t)row0*64 + (r*4+ct)*64 + q*16 + c] = f2bf(vacc[r]);
      float qc = (ct==0)?qv[r].x:(ct==1)?qv[r].y:(ct==2)?qv[r].z:qv[r].w;
      val[r*4+ct] += 0.25f * kacc[r] * qc;
    }
  }
  float qk = quad_butterfly16(val, c);   // lane c: (r=c>>2, h=c&3)
  int row = row0 + q*4 + (c>>2);
  float re = r2[row];
  // radial via table lerp: t = re/10*4096
  float t = re * ((float)RG/10.f);
  t = fminf(fmaxf(t, 0.f), (float)RG - 0.0001f);
  int i0 = (int)t;
  float fr = t - (float)i0;
  int h = c & 3;
  float lo = radtab[(size_t)i0*4 + h];
  float hi = radtab[(size_t)(i0+1)*4 + h];
  float logit = qk + lo + (hi - lo)*fr;
  exb[(size_t)row0*4 + lane] = (re < 10.f) ? __expf(logit) : 0.f;
}

// ---------------- softmax-denominator + aggregation; edges contiguous per node ----------------
__global__ __launch_bounds__(256) void k_agg(const int* rowptr, const float* exb, const u16* vbf, u16* aggbf, int N){
  int wave = (blockIdx.x*256 + threadIdx.x) >> 6;
  int lane = threadIdx.x & 63;
  if(wave >= N) return;
  int s0 = rowptr[wave], s1 = rowptr[wave+1];
  float s[4] = {0.f,0.f,0.f,0.f};
  for(int p = s0 + lane; p < s1; p += 64){
    float4 ev = *reinterpret_cast<const float4*>(exb + (size_t)p*4);
    s[0] += ev.x; s[1] += ev.y; s[2] += ev.z; s[3] += ev.w;
  }
  #pragma unroll
  for(int i=0;i<4;i++){ WREDUCE64(s[i]); }
  int ep = lane >> 4, cc = lane & 15;
  int hh = cc >> 2;
  int swz = hh*64 + (cc&3)*4;
  float inv = 1.f/(s[hh] + 1e-9f);
  float a0=0.f, a1=0.f, a2=0.f, a3=0.f;
  for(int p = s0 + ep; p < s1; p += 4){
    int t = p & 15;
    size_t base = (size_t)(p & ~15)*64 + (size_t)((t&3)*256) + (size_t)((t>>2)*16) + swz;
    ushort4 v4 = *reinterpret_cast<const ushort4*>(vbf + base);
    float ex = exb[(size_t)p*4 + hh];
    a0 += ex*bf2f(v4.x); a1 += ex*bf2f(v4.y); a2 += ex*bf2f(v4.z); a3 += ex*bf2f(v4.w);
  }
  a0 += __shfl_xor(a0,16); a0 += __shfl_xor(a0,32);
  a1 += __shfl_xor(a1,16); a1 += __shfl_xor(a1,32);
  a2 += __shfl_xor(a2,16); a2 += __shfl_xor(a2,32);
  a3 += __shfl_xor(a3,16); a3 += __shfl_xor(a3,32);
  if(ep == 0){
    ushort4 o;
    o.x = f2bf(a0*inv); o.y = f2bf(a1*inv); o.z = f2bf(a2*inv); o.w = f2bf(a3*inv);
    *reinterpret_cast<ushort4*>(aggbf + (size_t)wave*64 + cc*4) = o;
  }
}

// ---------------- MEGA: x+=agg@Wo; LN; FFN1; FFN2+residual; LN->hbf; Q_next->Qt ----------------
__global__ __launch_bounds__(256) void k_mega(const u16* aggbf, const u16* WoT, float* x,
    const u16* W1T, const u16* W2T, const u16* WqTn, float* Qt, u16* hbf, u16* xbf,
    int writex, int haveQ, int M){
  __shared__ u16 ldsH[4][16*72];
  __shared__ u16 ldsT[4][16*264];
  int widL = threadIdx.x >> 6;
  int wave = (blockIdx.x*256 + threadIdx.x) >> 6;
  int lane = threadIdx.x & 63;
  int row0 = wave*16; if(row0 >= M) return;
  int c = lane & 15, q = lane >> 4;
  u16* LH = ldsH[widL];
  u16* LT = ldsT[widL];
  {
    s8v a0 = *reinterpret_cast<const s8v*>(aggbf + (size_t)(row0+c)*64 + q*8);
    s8v a1 = *reinterpret_cast<const s8v*>(aggbf + (size_t)(row0+c)*64 + 32 + q*8);
    float nx[4][4];
    #pragma unroll
    for(int ct=0; ct<4; ct++){
      s8v b0 = *reinterpret_cast<const s8v*>(WoT + (ct*16+c)*64 + q*8);
      s8v b1 = *reinterpret_cast<const s8v*>(WoT + (ct*16+c)*64 + 32 + q*8);
      f32x4 acc = {0.f,0.f,0.f,0.f};
      acc = MFMA(a0, b0, acc);
      acc = MFMA(a1, b1, acc);
      #pragma unroll
      for(int r=0;r<4;r++){
        size_t idx = (size_t)(row0+q*4+r)*64 + ct*16 + c;
        float t = x[idx] + acc[r];
        x[idx] = t;
        nx[ct][r] = t;
      }
    }
    #pragma unroll
    for(int r=0;r<4;r++){
      float s = nx[0][r]+nx[1][r]+nx[2][r]+nx[3][r];
      QREDUCE16(s);
      float m = s*(1.f/64.f);
      float vv = 0.f;
      #pragma unroll
      for(int ct=0;ct<4;ct++){ float d = nx[ct][r]-m; vv += d*d; }
      QREDUCE16(vv);
      float rs = rsqrtf(vv*(1.f/64.f) + 1e-6f);
      #pragma unroll
      for(int ct=0;ct<4;ct++)
        LH[(q*4+r)*72 + ct*16 + c] = f2bf((nx[ct][r]-m)*rs);
    }
  }
  __syncthreads();
  {
    s8v h0 = *reinterpret_cast<const s8v*>(LH + c*72 + q*8);
    s8v h1 = *reinterpret_cast<const s8v*>(LH + c*72 + 32 + q*8);
    #pragma unroll
    for(int ct=0; ct<16; ct++){
      s8v b0 = *reinterpret_cast<const s8v*>(W1T + (ct*16+c)*64 + q*8);
      s8v b1 = *reinterpret_cast<const s8v*>(W1T + (ct*16+c)*64 + 32 + q*8);
      f32x4 acc = {0.f,0.f,0.f,0.f};
      acc = MFMA(h0, b0, acc);
      acc = MFMA(h1, b1, acc);
      #pragma unroll
      for(int r=0;r<4;r++){
        float y = acc[r];
        LT[(q*4+r)*264 + ct*16 + c] = f2bf(y / (1.f + __expf(-y)));
      }
    }
  }
  __syncthreads();
  {
    s8v a[8];
    #pragma unroll
    for(int kc=0; kc<8; kc++)
      a[kc] = *reinterpret_cast<const s8v*>(LT + c*264 + kc*32 + q*8);
    float nx[4][4];
    #pragma unroll
    for(int ct=0; ct<4; ct++){
      f32x4 acc = {0.f,0.f,0.f,0.f};
      #pragma unroll
      for(int kc=0; kc<8; kc++){
        s8v b = *reinterpret_cast<const s8v*>(W2T + (ct*16+c)*256 + kc*32 + q*8);
        acc = MFMA(a[kc], b, acc);
      }
      #pragma unroll
      for(int r=0;r<4;r++){
        size_t idx = (size_t)(row0+q*4+r)*64 + ct*16 + c;
        float t = x[idx] + acc[r];
        x[idx] = t;
        nx[ct][r] = t;
        if(writex) xbf[idx] = f2bf(t);
      }
    }
    #pragma unroll
    for(int r=0;r<4;r++){
      float s = nx[0][r]+nx[1][r]+nx[2][r]+nx[3][r];
      QREDUCE16(s);
      float m = s*(1.f/64.f);
      float vv = 0.f;
      #pragma unroll
      for(int ct=0;ct<4;ct++){ float d = nx[ct][r]-m; vv += d*d; }
      QREDUCE16(vv);
      float rs = rsqrtf(vv*(1.f/64.f) + 1e-6f);
      #pragma unroll
      for(int ct=0;ct<4;ct++){
        u16 hb = f2bf((nx[ct][r]-m)*rs);
        hbf[(size_t)(row0+q*4+r)*64 + ct*16 + c] = hb;
        LH[(q*4+r)*72 + ct*16 + c] = hb;
      }
    }
  }
  if(haveQ){
    s8v h0 = *reinterpret_cast<const s8v*>(LH + c*72 + q*8);
    s8v h1 = *reinterpret_cast<const s8v*>(LH + c*72 + 32 + q*8);
    #pragma unroll
    for(int ct=0; ct<4; ct++){
      s8v b0 = *reinterpret_cast<const s8v*>(WqTn + (ct*16+c)*64 + q*8);
      s8v b1 = *reinterpret_cast<const s8v*>(WqTn + (ct*16+c)*64 + 32 + q*8);
      f32x4 acc = {0.f,0.f,0.f,0.f};
      acc = MFMA(h0, b0, acc);
      acc = MFMA(h1, b1, acc);
      #pragma unroll
      for(int r=0;r<4;r++) Qt[(size_t)(row0+q*4+r)*64 + c*4 + ct] = acc[r];
    }
  }
}

// ---------------- feat = x @ W_feat with in-register LN over 512 -> featbf ----------------
__global__ __launch_bounds__(256) void k_feat_ln(const u16* A, const u16* Bt, u16* out, int M){
  int wave = (blockIdx.x*256 + threadIdx.x) >> 6;
  int lane = threadIdx.x & 63;
  int row0 = wave*16; if(row0 >= M) return;
  int c = lane & 15, q = lane >> 4;
  s8v a0 = *reinterpret_cast<const s8v*>(A + (size_t)(row0+c)*64 + q*8);
  s8v a1 = *reinterpret_cast<const s8v*>(A + (size_t)(row0+c)*64 + 32 + q*8);
  float fa[32][4];
  #pragma unroll
  for(int ct=0; ct<32; ct++){
    s8v b0 = *reinterpret_cast<const s8v*>(Bt + (ct*16+c)*64 + q*8);
    s8v b1 = *reinterpret_cast<const s8v*>(Bt + (ct*16+c)*64 + 32 + q*8);
    f32x4 acc = {0.f,0.f,0.f,0.f};
    acc = MFMA(a0, b0, acc);
    acc = MFMA(a1, b1, acc);
    #pragma unroll
    for(int r=0;r<4;r++) fa[ct][r] = acc[r];
  }
  #pragma unroll
  for(int r=0;r<4;r++){
    float s = 0.f;
    #pragma unroll
    for(int ct=0;ct<32;ct++) s += fa[ct][r];
    QREDUCE16(s);
    float m = s*(1.f/512.f);
    float vv = 0.f;
    #pragma unroll
    for(int ct=0;ct<32;ct++){ float d = fa[ct][r]-m; vv += d*d; }
    QREDUCE16(vv);
    float rs = rsqrtf(vv*(1.f/512.f) + 1e-6f);
    #pragma unroll
    for(int ct=0;ct<32;ct++)
      out[(size_t)(row0+q*4+r)*512 + ct*16 + c] = f2bf((fa[ct][r]-m)*rs);
  }
}

// ---------------- head1 (K=512) + bias + LN + relu -> hh1 ----------------
__global__ __launch_bounds__(256) void k_head1_ln(const u16* A, const u16* Bt, const float* hb, u16* out, int M){
  int wave = (blockIdx.x*256 + threadIdx.x) >> 6;
  int lane = threadIdx.x & 63;
  int row0 = wave*16; if(row0 >= M) return;
  int c = lane & 15, q = lane >> 4;
  s8v a[16];
  #pragma unroll
  for(int kc=0; kc<16; kc++)
    a[kc] = *reinterpret_cast<const s8v*>(A + (size_t)(row0+c)*512 + kc*32 + q*8);
  float y[4][4];
  #pragma unroll
  for(int ct=0; ct<4; ct++){
    f32x4 acc = {0.f,0.f,0.f,0.f};
    #pragma unroll
    for(int kc=0; kc<16; kc++){
      s8v b = *reinterpret_cast<const s8v*>(Bt + (size_t)(ct*16+c)*512 + kc*32 + q*8);
      acc = MFMA(a[kc], b, acc);
    }
    float bi = hb[ct*16+c];
    #pragma unroll
    for(int r=0;r<4;r++) y[ct][r] = acc[r] + bi;
  }
  #pragma unroll
  for(int r=0;r<4;r++){
    float s = y[0][r]+y[1][r]+y[2][r]+y[3][r];
    QREDUCE16(s);
    float m = s*(1.f/64.f);
    float vv = 0.f;
    #pragma unroll
    for(int ct=0;ct<4;ct++){ float d = y[ct][r]-m; vv += d*d; }
    QREDUCE16(vv);
    float rs = rsqrtf(vv*(1.f/64.f) + 1e-6f);
    #pragma unroll
    for(int ct=0;ct<4;ct++)
      out[(size_t)(row0+q*4+r)*64 + ct*16 + c] = f2bf(fmaxf((y[ct][r]-m)*rs, 0.f));
  }
}

// ---------------- head2 + bias + LN + relu + dot(hW3) + pooled atomicAdd ----------------
__global__ __launch_bounds__(256) void k_head2_energy(const u16* A, const u16* Bt, const float* hb,
    const float* hW3, const float* hb3, const int* batch, float* pooled, int M){
  int wave = (blockIdx.x*256 + threadIdx.x) >> 6;
  int lane = threadIdx.x & 63;
  int row0 = wave*16; if(row0 >= M) return;
  int c = lane & 15, q = lane >> 4;
  s8v a0 = *reinterpret_cast<const s8v*>(A + (size_t)(row0+c)*64 + q*8);
  s8v a1 = *reinterpret_cast<const s8v*>(A + (size_t)(row0+c)*64 + 32 + q*8);
  float y[4][4];
  #pragma unroll
  for(int ct=0; ct<4; ct++){
    s8v b0 = *reinterpret_cast<const s8v*>(Bt + (ct*16+c)*64 + q*8);
    s8v b1 = *reinterpret_cast<const s8v*>(Bt + (ct*16+c)*64 + 32 + q*8);
    f32x4 acc = {0.f,0.f,0.f,0.f};
    acc = MFMA(a0, b0, acc);
    acc = MFMA(a1, b1, acc);
    float bi = hb[ct*16+c];
    #pragma unroll
    for(int r=0;r<4;r++) y[ct][r] = acc[r] + bi;
  }
  float w3[4];
  #pragma unroll
  for(int ct=0;ct<4;ct++) w3[ct] = hW3[ct*16+c];
  float ep[4];
  #pragma unroll
  for(int r=0;r<4;r++){
    float s = y[0][r]+y[1][r]+y[2][r]+y[3][r];
    QREDUCE16(s);
    float m = s*(1.f/64.f);
    float vv = 0.f;
    #pragma unroll
    for(int ct=0;ct<4;ct++){ float d = y[ct][r]-m; vv += d*d; }
    QREDUCE16(vv);
    float rs = rsqrtf(vv*(1.f/64.f) + 1e-6f);
    float e = 0.f;
    #pragma unroll
    for(int ct=0;ct<4;ct++) e += fmaxf((y[ct][r]-m)*rs, 0.f) * w3[ct];
    QREDUCE16(e);
    ep[r] = e;
  }
  if(c < 4){
    float ev = (c==0)?ep[0]:(c==1)?ep[1]:(c==2)?ep[2]:ep[3];
    int row = row0 + q*4 + c;
    atomicAdd(&pooled[batch[row]], ev + hb3[0]);
  }
}

// ---------------- output f32 ----------------
__global__ __launch_bounds__(256) void k_out(const float* pooled, float* out, int G){
  int tid = blockIdx.x*256 + threadIdx.x;
  if(tid < G) out[tid] = pooled[tid] * 0.11785113019775793f; // 1/sqrt(72)
}

extern "C" void kernel_launch(void* const* d_in, const int* in_sizes, int n_in,
                              void* d_out, int out_size, void* d_ws, size_t ws_size,
                              hipStream_t stream){
  const int*   edge_src  = (const int*)d_in[1];
  const int*   edge_dst  = (const int*)d_in[2];
  const float* edge_vec  = (const float*)d_in[3];
  const int*   batch     = (const int*)d_in[4];
  const int*   node_atom = (const int*)d_in[5];
  const float* ele    = (const float*)d_in[6];
  const float* W_embed= (const float*)d_in[7];
  const float* W_edge = (const float*)d_in[8];
  const float* Wq = (const float*)d_in[9];
  const float* Wk = (const float*)d_in[10];
  const float* Wv = (const float*)d_in[11];
  const float* Wr1= (const float*)d_in[12];
  const float* Wr2= (const float*)d_in[13];
  const float* Wo = (const float*)d_in[14];
  const float* W1 = (const float*)d_in[15];
  const float* W2 = (const float*)d_in[16];
  const float* W_feat=(const float*)d_in[17];
  const float* hW1= (const float*)d_in[18];
  const float* hb1= (const float*)d_in[19];
  const float* hW2= (const float*)d_in[20];
  const float* hb2= (const float*)d_in[21];
  const float* hW3= (const float*)d_in[22];
  const float* hb3= (const float*)d_in[23];
  (void)n_in; (void)ws_size;

  const int E = in_sizes[1];
  const int N = in_sizes[4];
  const int G = out_size;

  // ---- workspace layout: peak ~90 MB ----
  char* base = (char*)d_ws;
  size_t off = 0;
  #define ALLOC(ty, name, count) ty* name = (ty*)(base + off); off = (off + (size_t)(count)*sizeof(ty) + 255) & ~(size_t)255;
  ALLOC(float, r2,    E)
  ALLOC(int,   src2,  E)
  ALLOC(int,   dst2,  E)
  ALLOC(u16,   ebf,   (size_t)E*64)
  ALLOC(u16,   vbf,   (size_t)E*64)
  ALLOC(float, exb,   (size_t)E*4)
  ALLOC(float, radtab,(size_t)6*RGROWS*4)
  ALLOC(u16,   hbf,   (size_t)N*64)
  ALLOC(u16,   aggbf, (size_t)N*64)
  ALLOC(u16,   xbf,   (size_t)N*64)
  ALLOC(float, Qt,    (size_t)N*64)
  ALLOC(float, xb,    (size_t)N*64)
  ALLOC(int,   deg,   N)
  ALLOC(int,   rowptr,N+1)
  ALLOC(int,   cursor,N)
  ALLOC(int,   csr,   E)
  ALLOC(float, pooled,G)
  // contiguous prep-region
  ALLOC(u16, ele_bf, 120*32)
  ALLOC(u16, WembT, 64*32)
  ALLOC(u16, WedgeT,64*160)
  ALLOC(u16, WqT,  6*64*64)
  ALLOC(u16, WkT,  6*64*64)
  ALLOC(u16, WvT,  6*64*64)
  ALLOC(u16, Wr1T, 6*64*64)
  ALLOC(u16, WoT,  6*64*64)
  ALLOC(u16, W1T,  6*256*64)
  ALLOC(u16, W2T,  6*64*256)
  ALLOC(u16, WfT,  512*64)
  ALLOC(u16, hW1T, 64*512)
  ALLOC(u16, hW2T, 64*64)
  #undef ALLOC
  // tail aliases into loop-dead regions:
  u16* featbf = ebf;          // 16 MB <= 32 MB
  u16* hh1    = (u16*)exb;    // 2 MB <= 4 MB

  auto cdiv = [](int a, int b){ return (a + b - 1)/b; };

  k_prep<<<cdiv(405248,256),256,0,stream>>>(ele, W_embed, W_edge, Wq, Wk, Wv, Wr1, Wo,
                                            W1, W2, W_feat, hW1, hW2, ele_bf);

  hipMemsetAsync(deg, 0, (size_t)N*sizeof(int), stream);
  hipMemsetAsync(pooled, 0, (size_t)G*sizeof(float), stream);

  k_count<<<cdiv(E,256),256,0,stream>>>(edge_dst, deg, E);
  k_scan<<<1,1024,0,stream>>>(deg, rowptr, cursor, N);
  k_scatter<<<cdiv(E,256),256,0,stream>>>(edge_dst, cursor, csr, E);
  k_edge_embed<<<E/64, 256, 0, stream>>>(csr, edge_src, edge_dst, node_atom, ele_bf, edge_vec,
                                         WedgeT, ebf, r2, src2, dst2, E);
  k_radtab<<<cdiv(RGROWS*4,256),256,0,stream>>>(Wr1T, Wr2, radtab);
  k_pre<<<N/64,256,0,stream>>>(node_atom, ele_bf, WembT, WqT, xb, hbf, Qt, N);

  for(int l=0; l<6; l++){
    k_kvrad<<<E/64,256,0,stream>>>(hbf, ebf, src2, dst2, Qt, r2, radtab + (size_t)l*RGROWS*4,
                                   WkT + l*4096, WvT + l*4096, vbf, exb, E);
    k_agg<<<cdiv(N,4),256,0,stream>>>(rowptr, exb, vbf, aggbf, N);
    k_mega<<<N/64,256,0,stream>>>(aggbf, WoT + l*4096, xb,
                                  W1T + l*16384, W2T + l*16384,
                                  WqT + ((l<5)?(l+1):0)*4096, Qt, hbf, xbf,
                                  (l==5)?1:0, (l<5)?1:0, N);
  }

  k_feat_ln<<<N/64,256,0,stream>>>(xbf, WfT, featbf, N);
  k_head1_ln<<<N/64,256,0,stream>>>(featbf, hW1T, hb1, hh1, N);
  k_head2_energy<<<N/64,256,0,stream>>>(hh1, hW2T, hb2, hW3, hb3, batch, pooled, N);
  k_out<<<cdiv(G,256),256,0,stream>>>(pooled, (float*)d_out, G);
}

// Round 16
// 674.881 us; speedup vs baseline: 1.2239x; 1.1094x over previous
//
#include <hip/hip_runtime.h>

typedef short s8v __attribute__((ext_vector_type(8)));
typedef float f32x4 __attribute__((ext_vector_type(4)));
typedef unsigned short u16;

__device__ __forceinline__ float bf2f(u16 h){
  union { unsigned u; float f; } v; v.u = ((unsigned)h) << 16; return v.f;
}
__device__ __forceinline__ u16 f2bf(float f){
  union { float f; unsigned u; } v; v.f = f;
  unsigned u = v.u;
  return (u16)((u + 0x7fffu + ((u >> 16) & 1u)) >> 16);
}
#define MFMA(a,b,c) __builtin_amdgcn_mfma_f32_16x16x32_bf16((a),(b),(c),0,0,0)

#define WREDUCE64(s) { s += __shfl_xor(s,1); s += __shfl_xor(s,2); s += __shfl_xor(s,4); \
                       s += __shfl_xor(s,8); s += __shfl_xor(s,16); s += __shfl_xor(s,32); }
#define QREDUCE16(s) { s += __shfl_xor(s,1); s += __shfl_xor(s,2); s += __shfl_xor(s,4); s += __shfl_xor(s,8); }

// 16-value butterfly within 16-lane quads: lane c (0..15) ends with sum-over-quad of val[c]
__device__ __forceinline__ float quad_butterfly16(float* val, int c){
  float v8[8], v4[4], v2[2];
  #pragma unroll
  for(int t=0;t<8;t++){
    float sent = (c&1) ? val[2*t] : val[2*t+1];
    float got = __shfl_xor(sent, 1);
    v8[t] = ((c&1) ? val[2*t+1] : val[2*t]) + got;
  }
  #pragma unroll
  for(int t=0;t<4;t++){
    float sent = ((c>>1)&1) ? v8[2*t] : v8[2*t+1];
    float got = __shfl_xor(sent, 2);
    v4[t] = (((c>>1)&1) ? v8[2*t+1] : v8[2*t]) + got;
  }
  #pragma unroll
  for(int t=0;t<2;t++){
    float sent = ((c>>2)&1) ? v4[2*t] : v4[2*t+1];
    float got = __shfl_xor(sent, 4);
    v2[t] = (((c>>2)&1) ? v4[2*t+1] : v4[2*t]) + got;
  }
  float sent = ((c>>3)&1) ? v2[0] : v2[1];
  float got = __shfl_xor(sent, 8);
  return (((c>>3)&1) ? v2[1] : v2[0]) + got;
}

// ---------------- ONE-SHOT prep: convert + all weight transposes (contiguous dst regions) ----------------
__global__ __launch_bounds__(256) void k_prep(const float* ele, const float* W_embed, const float* W_edge,
    const float* Wq, const float* Wk, const float* Wv, const float* Wr1, const float* Wo,
    const float* W1, const float* W2, const float* W_feat, const float* hW1, const float* hW2,
    u16* dst){
  int idx = blockIdx.x*256 + threadIdx.x;
  if(idx >= 405248) return;
  u16 v;
  if(idx < 3840){                    // ele convert
    v = f2bf(ele[idx]);
  } else if(idx < 5888){             // WembT: R=32,C=64,Rpad=32
    int l = idx - 3840;
    int cI = l >> 5, rI = l & 31;
    v = f2bf(W_embed[rI*64 + cI]);
  } else if(idx < 16128){            // WedgeT: R=137,C=64,Rpad=160
    int l = idx - 5888;
    int cI = l / 160, rI = l - cI*160;
    v = (rI < 137) ? f2bf(W_edge[rI*64 + cI]) : (u16)0;
  } else if(idx < 139008){           // Wq,Wk,Wv,Wr1,Wo: 5 x 6 x 64x64
    int l = idx - 16128;
    int which = l / 24576;
    int rem = l - which*24576;
    const float* src = (which==0)?Wq:(which==1)?Wk:(which==2)?Wv:(which==3)?Wr1:Wo;
    int b = rem >> 12;
    int r2 = rem & 4095;
    int cI = r2 >> 6, rI = r2 & 63;
    v = f2bf(src[b*4096 + rI*64 + cI]);
  } else if(idx < 237312){           // W1T: B=6,R=64,C=256,Rpad=64
    int l = idx - 139008;
    int b = l / 16384;
    int rem = l - b*16384;
    int cI = rem >> 6, rI = rem & 63;
    v = f2bf(W1[b*16384 + rI*256 + cI]);
  } else if(idx < 335616){           // W2T: B=6,R=256,C=64,Rpad=256
    int l = idx - 237312;
    int b = l / 16384;
    int rem = l - b*16384;
    int cI = rem >> 8, rI = rem & 255;
    v = f2bf(W2[b*16384 + rI*64 + cI]);
  } else if(idx < 368384){           // WfT: R=64,C=512,Rpad=64
    int l = idx - 335616;
    int cI = l >> 6, rI = l & 63;
    v = f2bf(W_feat[rI*512 + cI]);
  } else if(idx < 401152){           // hW1T: R=512,C=64,Rpad=512
    int l = idx - 368384;
    int cI = l >> 9, rI = l & 511;
    v = f2bf(hW1[rI*64 + cI]);
  } else {                           // hW2T: R=64,C=64
    int l = idx - 401152;
    int cI = l >> 6, rI = l & 63;
    v = f2bf(hW2[rI*64 + cI]);
  }
  dst[idx] = v;
}

// ---------------- CSR build ----------------
__global__ __launch_bounds__(256) void k_count(const int* dstI, int* deg, int E){
  int tid = blockIdx.x*256 + threadIdx.x;
  if(tid < E) atomicAdd(&deg[dstI[tid]], 1);
}
__global__ __launch_bounds__(1024) void k_scan(const int* deg, int* rowptr, int* cursor, int N){
  __shared__ int wsum[17];
  int tid = threadIdx.x;
  int per = (N + 1023) >> 10;
  int base = tid * per;
  int s = 0;
  for(int i=0;i<per;i++){ int idx = base+i; if(idx < N) s += deg[idx]; }
  int lane = tid & 63, wid = tid >> 6;
  int inc = s;
  for(int d=1; d<64; d<<=1){
    int t = __shfl_up(inc, d);
    if(lane >= d) inc += t;
  }
  if(lane == 63) wsum[wid+1] = inc;
  if(tid == 0) wsum[0] = 0;
  __syncthreads();
  if(tid == 0){ for(int w=1; w<=16; w++) wsum[w] += wsum[w-1]; }
  __syncthreads();
  int run = inc - s + wsum[wid];
  for(int i=0;i<per;i++){
    int idx = base + i;
    if(idx < N){ rowptr[idx] = run; cursor[idx] = run; run += deg[idx]; }
  }
  if(tid == 1023) rowptr[N] = wsum[16];
}
__global__ __launch_bounds__(256) void k_scatter(const int* dstI, int* cursor, int* csr, int E){
  int tid = blockIdx.x*256 + threadIdx.x;
  if(tid < E){
    int p = atomicAdd(&cursor[dstI[tid]], 1);
    csr[p] = tid;
  }
}

// ---------------- e = [nf_src, nf_dst, sh, rbf] @ W_edge in CSR-PERMUTED order ----------------
__global__ __launch_bounds__(256) void k_edge_embed(const int* csr, const int* srcI, const int* dstI,
    const int* atom, const u16* ele, const float* evec, const u16* Bt,
    u16* ebf, float* r2, int* src2, int* dst2, int E){
  int wave = (blockIdx.x*blockDim.x + threadIdx.x) >> 6;
  int lane = threadIdx.x & 63;
  int row0 = wave*16; if(row0 >= E) return;
  int c = lane & 15, q = lane >> 4;
  int p = row0 + c;
  int e = csr[p];
  int sn = srcI[e], dn = dstI[e];
  float vx = evec[(size_t)e*3+0];
  float vy = evec[(size_t)e*3+1];
  float vz = evec[(size_t)e*3+2];
  float r = sqrtf(vx*vx + vy*vy + vz*vz);
  if(q == 0){ r2[p] = r; src2[p] = sn; dst2[p] = dn; }
  float inv = 1.f/(r + 1e-12f);
  // u = edge_vec[:, [1,2,0]] / r -> x=v1, y=v2, z=v0
  float x = vy*inv, y = vz*inv, z = vx*inv;
  const float s3 = 1.7320508075688772f, s15 = 3.872983346207417f;
  const float s5h = 1.118033988749895f, s15h = 1.9364916731037085f;
  float sh[9];
  sh[0] = 1.f; sh[1] = s3*x; sh[2] = s3*y; sh[3] = s3*z;
  sh[4] = s15*x*y; sh[5] = s15*y*z; sh[6] = s5h*(3.f*z*z - 1.f);
  sh[7] = s15*x*z; sh[8] = s15h*(x*x - y*y);
  s8v a[5];
  a[0] = *reinterpret_cast<const s8v*>(ele + (size_t)atom[sn]*32 + q*8);
  a[1] = *reinterpret_cast<const s8v*>(ele + (size_t)atom[dn]*32 + q*8);
  #pragma unroll
  for(int j=0;j<8;j++){
    int col = 64 + q*8 + j;
    u16 v;
    if(q == 0)            v = f2bf(sh[j]);
    else if(col < 73)     v = f2bf(sh[8]);
    else { float d = r - (10.f/63.f)*(float)(col-73); v = f2bf(__expf(-81.92f*d*d)); }
    a[2][j] = (short)v;
  }
  #pragma unroll
  for(int j=0;j<8;j++){
    float d = r - (10.f/63.f)*(float)(23 + q*8 + j);
    a[3][j] = (short)f2bf(__expf(-81.92f*d*d));
  }
  #pragma unroll
  for(int j=0;j<8;j++){
    int col = 128 + q*8 + j;
    u16 v = 0;
    if(col < 137){ float d = r - (10.f/63.f)*(float)(col-73); v = f2bf(__expf(-81.92f*d*d)); }
    a[4][j] = (short)v;
  }
  #pragma unroll
  for(int ct=0; ct<4; ct++){
    f32x4 acc = {0.f,0.f,0.f,0.f};
    #pragma unroll
    for(int kc=0; kc<5; kc++){
      s8v b = *reinterpret_cast<const s8v*>(Bt + (ct*16+c)*160 + kc*32 + q*8);
      acc = MFMA(a[kc], b, acc);
    }
    #pragma unroll
    for(int r_=0;r_<4;r_++) ebf[(size_t)(row0+q*4+r_)*64 + ct*16 + c] = f2bf(acc[r_]);
  }
}

// ---------------- one-shot: radial TABLE over r-grid [0,10], 4096 intervals, all 6 layers ----------------
#define RG 4096
#define RGROWS 4112
__global__ __launch_bounds__(256) void k_radtab(const u16* Wr1T, const float* Wr2, float* radtab){
  int wave = (blockIdx.x*256 + threadIdx.x) >> 6;
  int lane = threadIdx.x & 63;
  int row0 = wave*16; if(row0 >= RGROWS) return;
  int c = lane & 15, q = lane >> 4;
  float re = (10.f/RG)*(float)(row0 + c);
  s8v r0, r1;
  #pragma unroll
  for(int j=0;j<8;j++){
    float d0 = re - (10.f/63.f)*(float)(q*8+j);
    float d1 = re - (10.f/63.f)*(float)(32+q*8+j);
    r0[j] = (short)f2bf(__expf(-81.92f*d0*d0));
    r1[j] = (short)f2bf(__expf(-81.92f*d1*d1));
  }
  for(int l=0; l<6; l++){
    const u16* W1l = Wr1T + l*4096;
    const float4* wr2v = reinterpret_cast<const float4*>(Wr2 + l*256);
    float val[16];
    #pragma unroll
    for(int i=0;i<16;i++) val[i] = 0.f;
    #pragma unroll
    for(int ct=0; ct<4; ct++){
      s8v bw0 = *reinterpret_cast<const s8v*>(W1l + (ct*16+c)*64 + q*8);
      s8v bw1 = *reinterpret_cast<const s8v*>(W1l + (ct*16+c)*64 + 32 + q*8);
      f32x4 hacc = {0.f,0.f,0.f,0.f};
      hacc = MFMA(r0, bw0, hacc); hacc = MFMA(r1, bw1, hacc);
      float4 w2 = wr2v[ct*16 + c];
      #pragma unroll
      for(int r=0;r<4;r++){
        float y = hacc[r];
        float sv = y / (1.f + __expf(-y));
        val[r*4+0] += sv * w2.x;
        val[r*4+1] += sv * w2.y;
        val[r*4+2] += sv * w2.z;
        val[r*4+3] += sv * w2.w;
      }
    }
    float fin = quad_butterfly16(val, c);
    int row = row0 + q*4 + (c>>2);
    if(row <= RG)
      radtab[(size_t)l*RGROWS*4 + (size_t)row0*4 + lane] = fin;
  }
}

// ---------------- pre: x = ele[atom]@Wemb; h0 = LN(x); Q0 = h0@Wq0 (Qt layout) ----------------
__global__ __launch_bounds__(256) void k_pre(const int* atom, const u16* ele, const u16* WembT,
    const u16* WqT0, float* xb, u16* hbf, float* Qt, int M){
  __shared__ u16 ldsH[4][16*72];
  int widL = threadIdx.x >> 6;
  int wave = (blockIdx.x*256 + threadIdx.x) >> 6;
  int lane = threadIdx.x & 63;
  int row0 = wave*16; if(row0 >= M) return;
  int c = lane & 15, q = lane >> 4;
  u16* LH = ldsH[widL];
  int at = atom[row0 + c];
  s8v a = *reinterpret_cast<const s8v*>(ele + (size_t)at*32 + q*8);
  float nx[4][4];
  #pragma unroll
  for(int ct=0; ct<4; ct++){
    s8v b = *reinterpret_cast<const s8v*>(WembT + (ct*16+c)*32 + q*8);
    f32x4 acc = {0.f,0.f,0.f,0.f};
    acc = MFMA(a, b, acc);
    #pragma unroll
    for(int r=0;r<4;r++){
      xb[(size_t)(row0+q*4+r)*64 + ct*16 + c] = acc[r];
      nx[ct][r] = acc[r];
    }
  }
  #pragma unroll
  for(int r=0;r<4;r++){
    float s = nx[0][r]+nx[1][r]+nx[2][r]+nx[3][r];
    QREDUCE16(s);
    float m = s*(1.f/64.f);
    float vv = 0.f;
    #pragma unroll
    for(int ct=0;ct<4;ct++){ float d = nx[ct][r]-m; vv += d*d; }
    QREDUCE16(vv);
    float rs = rsqrtf(vv*(1.f/64.f) + 1e-6f);
    #pragma unroll
    for(int ct=0;ct<4;ct++){
      u16 hb = f2bf((nx[ct][r]-m)*rs);
      hbf[(size_t)(row0+q*4+r)*64 + ct*16 + c] = hb;
      LH[(q*4+r)*72 + ct*16 + c] = hb;
    }
  }
  s8v h0 = *reinterpret_cast<const s8v*>(LH + c*72 + q*8);
  s8v h1 = *reinterpret_cast<const s8v*>(LH + c*72 + 32 + q*8);
  #pragma unroll
  for(int ct=0; ct<4; ct++){
    s8v b0 = *reinterpret_cast<const s8v*>(WqT0 + (ct*16+c)*64 + q*8);
    s8v b1 = *reinterpret_cast<const s8v*>(WqT0 + (ct*16+c)*64 + 32 + q*8);
    f32x4 acc = {0.f,0.f,0.f,0.f};
    acc = MFMA(h0, b0, acc);
    acc = MFMA(h1, b1, acc);
    #pragma unroll
    for(int r=0;r<4;r++) Qt[(size_t)(row0+q*4+r)*64 + c*4 + ct] = acc[r];
  }
}

// ---------------- fused k,v MFMAs + qk logits + radial lerp + exp; TWO tiles per wave ----------------
__global__ __launch_bounds__(256) void k_kvrad(const u16* hbf, const u16* ebf,
    const int* src2, const int* dst2, const float* Qt, const float* r2, const float* radtab,
    const u16* WkT, const u16* WvT, u16* vbf, float* exb, int E){
  int wave = (blockIdx.x*256 + threadIdx.x) >> 6;
  int lane = threadIdx.x & 63;
  int base0 = wave*32;
  if(base0 >= E) return;
  int c = lane & 15, q = lane >> 4;
  // build A-fragments for both tiles (loads issue up front -> 2x MLP)
  s8v a0[2], a1[2];
  #pragma unroll
  for(int t=0;t<2;t++){
    int row0 = base0 + t*16;
    int sr = src2[row0 + c];
    s8v h0 = *reinterpret_cast<const s8v*>(hbf + (size_t)sr*64 + q*8);
    s8v h1 = *reinterpret_cast<const s8v*>(hbf + (size_t)sr*64 + 32 + q*8);
    s8v e0 = *reinterpret_cast<const s8v*>(ebf + (size_t)(row0+c)*64 + q*8);
    s8v e1 = *reinterpret_cast<const s8v*>(ebf + (size_t)(row0+c)*64 + 32 + q*8);
    #pragma unroll
    for(int j=0;j<8;j++){
      a0[t][j] = (short)f2bf(bf2f((u16)h0[j]) + bf2f((u16)e0[j]));
      a1[t][j] = (short)f2bf(bf2f((u16)h1[j]) + bf2f((u16)e1[j]));
    }
  }
  const float4* QtV = reinterpret_cast<const float4*>(Qt);
  float4 qv[2][4];
  #pragma unroll
  for(int t=0;t<2;t++)
    #pragma unroll
    for(int r=0;r<4;r++){
      int dr = dst2[base0 + t*16 + q*4 + r];
      qv[t][r] = QtV[(size_t)dr*16 + c];
    }
  float val[2][16];
  #pragma unroll
  for(int t=0;t<2;t++)
    #pragma unroll
    for(int i=0;i<16;i++) val[t][i] = 0.f;
  #pragma unroll
  for(int ct=0; ct<4; ct++){
    // weight fragments shared by both tiles
    s8v bk0 = *reinterpret_cast<const s8v*>(WkT + (ct*16+c)*64 + q*8);
    s8v bk1 = *reinterpret_cast<const s8v*>(WkT + (ct*16+c)*64 + 32 + q*8);
    s8v bv0 = *reinterpret_cast<const s8v*>(WvT + (ct*16+c)*64 + q*8);
    s8v bv1 = *reinterpret_cast<const s8v*>(WvT + (ct*16+c)*64 + 32 + q*8);
    #pragma unroll
    for(int t=0;t<2;t++){
      int row0 = base0 + t*16;
      f32x4 kacc = {0.f,0.f,0.f,0.f};
      kacc = MFMA(a0[t], bk0, kacc); kacc = MFMA(a1[t], bk1, kacc);
      f32x4 vacc = {0.f,0.f,0.f,0.f};
      vacc = MFMA(a0[t], bv0, vacc); vacc = MFMA(a1[t], bv1, vacc);
      #pragma unroll
      for(int r=0;r<4;r++){
        vbf[(size_t)row0*64 + (r*4+ct)*64 + q*16 + c] = f2bf(vacc[r]);
        float qc = (ct==0)?qv[t][r].x:(ct==1)?qv[t][r].y:(ct==2)?qv[t][r].z:qv[t][r].w;
        val[t][r*4+ct] += 0.25f * kacc[r] * qc;
      }
    }
  }
  #pragma unroll
  for(int t=0;t<2;t++){
    int row0 = base0 + t*16;
    float qk = quad_butterfly16(val[t], c);   // lane c: (r=c>>2, h=c&3)
    int row = row0 + q*4 + (c>>2);
    float re = r2[row];
    float tt = re * ((float)RG/10.f);
    tt = fminf(fmaxf(tt, 0.f), (float)RG - 0.0001f);
    int i0 = (int)tt;
    float fr = tt - (float)i0;
    int h = c & 3;
    float lo = radtab[(size_t)i0*4 + h];
    float hi = radtab[(size_t)(i0+1)*4 + h];
    float logit = qk + lo + (hi - lo)*fr;
    exb[(size_t)row0*4 + lane] = (re < 10.f) ? __expf(logit) : 0.f;
  }
}

// ---------------- softmax-denominator + aggregation; edges contiguous per node ----------------
__global__ __launch_bounds__(256) void k_agg(const int* rowptr, const float* exb, const u16* vbf, u16* aggbf, int N){
  int wave = (blockIdx.x*256 + threadIdx.x) >> 6;
  int lane = threadIdx.x & 63;
  if(wave >= N) return;
  int s0 = rowptr[wave], s1 = rowptr[wave+1];
  float s[4] = {0.f,0.f,0.f,0.f};
  for(int p = s0 + lane; p < s1; p += 64){
    float4 ev = *reinterpret_cast<const float4*>(exb + (size_t)p*4);
    s[0] += ev.x; s[1] += ev.y; s[2] += ev.z; s[3] += ev.w;
  }
  #pragma unroll
  for(int i=0;i<4;i++){ WREDUCE64(s[i]); }
  int ep = lane >> 4, cc = lane & 15;
  int hh = cc >> 2;
  int swz = hh*64 + (cc&3)*4;
  float inv = 1.f/(s[hh] + 1e-9f);
  float a0=0.f, a1=0.f, a2=0.f, a3=0.f;
  for(int p = s0 + ep; p < s1; p += 4){
    int t = p & 15;
    size_t base = (size_t)(p & ~15)*64 + (size_t)((t&3)*256) + (size_t)((t>>2)*16) + swz;
    ushort4 v4 = *reinterpret_cast<const ushort4*>(vbf + base);
    float ex = exb[(size_t)p*4 + hh];
    a0 += ex*bf2f(v4.x); a1 += ex*bf2f(v4.y); a2 += ex*bf2f(v4.z); a3 += ex*bf2f(v4.w);
  }
  a0 += __shfl_xor(a0,16); a0 += __shfl_xor(a0,32);
  a1 += __shfl_xor(a1,16); a1 += __shfl_xor(a1,32);
  a2 += __shfl_xor(a2,16); a2 += __shfl_xor(a2,32);
  a3 += __shfl_xor(a3,16); a3 += __shfl_xor(a3,32);
  if(ep == 0){
    ushort4 o;
    o.x = f2bf(a0*inv); o.y = f2bf(a1*inv); o.z = f2bf(a2*inv); o.w = f2bf(a3*inv);
    *reinterpret_cast<ushort4*>(aggbf + (size_t)wave*64 + cc*4) = o;
  }
}

// ---------------- MEGA: x+=agg@Wo; LN; FFN1; FFN2+residual; LN->hbf; Q_next->Qt ----------------
__global__ __launch_bounds__(256) void k_mega(const u16* aggbf, const u16* WoT, float* x,
    const u16* W1T, const u16* W2T, const u16* WqTn, float* Qt, u16* hbf, u16* xbf,
    int writex, int haveQ, int M){
  __shared__ u16 ldsH[4][16*72];
  __shared__ u16 ldsT[4][16*264];
  int widL = threadIdx.x >> 6;
  int wave = (blockIdx.x*256 + threadIdx.x) >> 6;
  int lane = threadIdx.x & 63;
  int row0 = wave*16; if(row0 >= M) return;
  int c = lane & 15, q = lane >> 4;
  u16* LH = ldsH[widL];
  u16* LT = ldsT[widL];
  {
    s8v a0 = *reinterpret_cast<const s8v*>(aggbf + (size_t)(row0+c)*64 + q*8);
    s8v a1 = *reinterpret_cast<const s8v*>(aggbf + (size_t)(row0+c)*64 + 32 + q*8);
    float nx[4][4];
    #pragma unroll
    for(int ct=0; ct<4; ct++){
      s8v b0 = *reinterpret_cast<const s8v*>(WoT + (ct*16+c)*64 + q*8);
      s8v b1 = *reinterpret_cast<const s8v*>(WoT + (ct*16+c)*64 + 32 + q*8);
      f32x4 acc = {0.f,0.f,0.f,0.f};
      acc = MFMA(a0, b0, acc);
      acc = MFMA(a1, b1, acc);
      #pragma unroll
      for(int r=0;r<4;r++){
        size_t idx = (size_t)(row0+q*4+r)*64 + ct*16 + c;
        float t = x[idx] + acc[r];
        x[idx] = t;
        nx[ct][r] = t;
      }
    }
    #pragma unroll
    for(int r=0;r<4;r++){
      float s = nx[0][r]+nx[1][r]+nx[2][r]+nx[3][r];
      QREDUCE16(s);
      float m = s*(1.f/64.f);
      float vv = 0.f;
      #pragma unroll
      for(int ct=0;ct<4;ct++){ float d = nx[ct][r]-m; vv += d*d; }
      QREDUCE16(vv);
      float rs = rsqrtf(vv*(1.f/64.f) + 1e-6f);
      #pragma unroll
      for(int ct=0;ct<4;ct++)
        LH[(q*4+r)*72 + ct*16 + c] = f2bf((nx[ct][r]-m)*rs);
    }
  }
  __syncthreads();
  {
    s8v h0 = *reinterpret_cast<const s8v*>(LH + c*72 + q*8);
    s8v h1 = *reinterpret_cast<const s8v*>(LH + c*72 + 32 + q*8);
    #pragma unroll
    for(int ct=0; ct<16; ct++){
      s8v b0 = *reinterpret_cast<const s8v*>(W1T + (ct*16+c)*64 + q*8);
      s8v b1 = *reinterpret_cast<const s8v*>(W1T + (ct*16+c)*64 + 32 + q*8);
      f32x4 acc = {0.f,0.f,0.f,0.f};
      acc = MFMA(h0, b0, acc);
      acc = MFMA(h1, b1, acc);
      #pragma unroll
      for(int r=0;r<4;r++){
        float y = acc[r];
        LT[(q*4+r)*264 + ct*16 + c] = f2bf(y / (1.f + __expf(-y)));
      }
    }
  }
  __syncthreads();
  {
    s8v a[8];
    #pragma unroll
    for(int kc=0; kc<8; kc++)
      a[kc] = *reinterpret_cast<const s8v*>(LT + c*264 + kc*32 + q*8);
    float nx[4][4];
    #pragma unroll
    for(int ct=0; ct<4; ct++){
      f32x4 acc = {0.f,0.f,0.f,0.f};
      #pragma unroll
      for(int kc=0; kc<8; kc++){
        s8v b = *reinterpret_cast<const s8v*>(W2T + (ct*16+c)*256 + kc*32 + q*8);
        acc = MFMA(a[kc], b, acc);
      }
      #pragma unroll
      for(int r=0;r<4;r++){
        size_t idx = (size_t)(row0+q*4+r)*64 + ct*16 + c;
        float t = x[idx] + acc[r];
        x[idx] = t;
        nx[ct][r] = t;
        if(writex) xbf[idx] = f2bf(t);
      }
    }
    #pragma unroll
    for(int r=0;r<4;r++){
      float s = nx[0][r]+nx[1][r]+nx[2][r]+nx[3][r];
      QREDUCE16(s);
      float m = s*(1.f/64.f);
      float vv = 0.f;
      #pragma unroll
      for(int ct=0;ct<4;ct++){ float d = nx[ct][r]-m; vv += d*d; }
      QREDUCE16(vv);
      float rs = rsqrtf(vv*(1.f/64.f) + 1e-6f);
      #pragma unroll
      for(int ct=0;ct<4;ct++){
        u16 hb = f2bf((nx[ct][r]-m)*rs);
        hbf[(size_t)(row0+q*4+r)*64 + ct*16 + c] = hb;
        LH[(q*4+r)*72 + ct*16 + c] = hb;
      }
    }
  }
  if(haveQ){
    s8v h0 = *reinterpret_cast<const s8v*>(LH + c*72 + q*8);
    s8v h1 = *reinterpret_cast<const s8v*>(LH + c*72 + 32 + q*8);
    #pragma unroll
    for(int ct=0; ct<4; ct++){
      s8v b0 = *reinterpret_cast<const s8v*>(WqTn + (ct*16+c)*64 + q*8);
      s8v b1 = *reinterpret_cast<const s8v*>(WqTn + (ct*16+c)*64 + 32 + q*8);
      f32x4 acc = {0.f,0.f,0.f,0.f};
      acc = MFMA(h0, b0, acc);
      acc = MFMA(h1, b1, acc);
      #pragma unroll
      for(int r=0;r<4;r++) Qt[(size_t)(row0+q*4+r)*64 + c*4 + ct] = acc[r];
    }
  }
}

// ---------------- feat = x @ W_feat with in-register LN over 512 -> featbf ----------------
__global__ __launch_bounds__(256) void k_feat_ln(const u16* A, const u16* Bt, u16* out, int M){
  int wave = (blockIdx.x*256 + threadIdx.x) >> 6;
  int lane = threadIdx.x & 63;
  int row0 = wave*16; if(row0 >= M) return;
  int c = lane & 15, q = lane >> 4;
  s8v a0 = *reinterpret_cast<const s8v*>(A + (size_t)(row0+c)*64 + q*8);
  s8v a1 = *reinterpret_cast<const s8v*>(A + (size_t)(row0+c)*64 + 32 + q*8);
  float fa[32][4];
  #pragma unroll
  for(int ct=0; ct<32; ct++){
    s8v b0 = *reinterpret_cast<const s8v*>(Bt + (ct*16+c)*64 + q*8);
    s8v b1 = *reinterpret_cast<const s8v*>(Bt + (ct*16+c)*64 + 32 + q*8);
    f32x4 acc = {0.f,0.f,0.f,0.f};
    acc = MFMA(a0, b0, acc);
    acc = MFMA(a1, b1, acc);
    #pragma unroll
    for(int r=0;r<4;r++) fa[ct][r] = acc[r];
  }
  #pragma unroll
  for(int r=0;r<4;r++){
    float s = 0.f;
    #pragma unroll
    for(int ct=0;ct<32;ct++) s += fa[ct][r];
    QREDUCE16(s);
    float m = s*(1.f/512.f);
    float vv = 0.f;
    #pragma unroll
    for(int ct=0;ct<32;ct++){ float d = fa[ct][r]-m; vv += d*d; }
    QREDUCE16(vv);
    float rs = rsqrtf(vv*(1.f/512.f) + 1e-6f);
    #pragma unroll
    for(int ct=0;ct<32;ct++)
      out[(size_t)(row0+q*4+r)*512 + ct*16 + c] = f2bf((fa[ct][r]-m)*rs);
  }
}

// ---------------- head1 (K=512) + bias + LN + relu -> hh1 ----------------
__global__ __launch_bounds__(256) void k_head1_ln(const u16* A, const u16* Bt, const float* hb, u16* out, int M){
  int wave = (blockIdx.x*256 + threadIdx.x) >> 6;
  int lane = threadIdx.x & 63;
  int row0 = wave*16; if(row0 >= M) return;
  int c = lane & 15, q = lane >> 4;
  s8v a[16];
  #pragma unroll
  for(int kc=0; kc<16; kc++)
    a[kc] = *reinterpret_cast<const s8v*>(A + (size_t)(row0+c)*512 + kc*32 + q*8);
  float y[4][4];
  #pragma unroll
  for(int ct=0; ct<4; ct++){
    f32x4 acc = {0.f,0.f,0.f,0.f};
    #pragma unroll
    for(int kc=0; kc<16; kc++){
      s8v b = *reinterpret_cast<const s8v*>(Bt + (size_t)(ct*16+c)*512 + kc*32 + q*8);
      acc = MFMA(a[kc], b, acc);
    }
    float bi = hb[ct*16+c];
    #pragma unroll
    for(int r=0;r<4;r++) y[ct][r] = acc[r] + bi;
  }
  #pragma unroll
  for(int r=0;r<4;r++){
    float s = y[0][r]+y[1][r]+y[2][r]+y[3][r];
    QREDUCE16(s);
    float m = s*(1.f/64.f);
    float vv = 0.f;
    #pragma unroll
    for(int ct=0;ct<4;ct++){ float d = y[ct][r]-m; vv += d*d; }
    QREDUCE16(vv);
    float rs = rsqrtf(vv*(1.f/64.f) + 1e-6f);
    #pragma unroll
    for(int ct=0;ct<4;ct++)
      out[(size_t)(row0+q*4+r)*64 + ct*16 + c] = f2bf(fmaxf((y[ct][r]-m)*rs, 0.f));
  }
}

// ---------------- head2 + bias + LN + relu + dot(hW3) + pooled atomicAdd ----------------
__global__ __launch_bounds__(256) void k_head2_energy(const u16* A, const u16* Bt, const float* hb,
    const float* hW3, const float* hb3, const int* batch, float* pooled, int M){
  int wave = (blockIdx.x*256 + threadIdx.x) >> 6;
  int lane = threadIdx.x & 63;
  int row0 = wave*16; if(row0 >= M) return;
  int c = lane & 15, q = lane >> 4;
  s8v a0 = *reinterpret_cast<const s8v*>(A + (size_t)(row0+c)*64 + q*8);
  s8v a1 = *reinterpret_cast<const s8v*>(A + (size_t)(row0+c)*64 + 32 + q*8);
  float y[4][4];
  #pragma unroll
  for(int ct=0; ct<4; ct++){
    s8v b0 = *reinterpret_cast<const s8v*>(Bt + (ct*16+c)*64 + q*8);
    s8v b1 = *reinterpret_cast<const s8v*>(Bt + (ct*16+c)*64 + 32 + q*8);
    f32x4 acc = {0.f,0.f,0.f,0.f};
    acc = MFMA(a0, b0, acc);
    acc = MFMA(a1, b1, acc);
    float bi = hb[ct*16+c];
    #pragma unroll
    for(int r=0;r<4;r++) y[ct][r] = acc[r] + bi;
  }
  float w3[4];
  #pragma unroll
  for(int ct=0;ct<4;ct++) w3[ct] = hW3[ct*16+c];
  float ep[4];
  #pragma unroll
  for(int r=0;r<4;r++){
    float s = y[0][r]+y[1][r]+y[2][r]+y[3][r];
    QREDUCE16(s);
    float m = s*(1.f/64.f);
    float vv = 0.f;
    #pragma unroll
    for(int ct=0;ct<4;ct++){ float d = y[ct][r]-m; vv += d*d; }
    QREDUCE16(vv);
    float rs = rsqrtf(vv*(1.f/64.f) + 1e-6f);
    float e = 0.f;
    #pragma unroll
    for(int ct=0;ct<4;ct++) e += fmaxf((y[ct][r]-m)*rs, 0.f) * w3[ct];
    QREDUCE16(e);
    ep[r] = e;
  }
  if(c < 4){
    float ev = (c==0)?ep[0]:(c==1)?ep[1]:(c==2)?ep[2]:ep[3];
    int row = row0 + q*4 + c;
    atomicAdd(&pooled[batch[row]], ev + hb3[0]);
  }
}

// ---------------- output f32 ----------------
__global__ __launch_bounds__(256) void k_out(const float* pooled, float* out, int G){
  int tid = blockIdx.x*256 + threadIdx.x;
  if(tid < G) out[tid] = pooled[tid] * 0.11785113019775793f; // 1/sqrt(72)
}

extern "C" void kernel_launch(void* const* d_in, const int* in_sizes, int n_in,
                              void* d_out, int out_size, void* d_ws, size_t ws_size,
                              hipStream_t stream){
  const int*   edge_src  = (const int*)d_in[1];
  const int*   edge_dst  = (const int*)d_in[2];
  const float* edge_vec  = (const float*)d_in[3];
  const int*   batch     = (const int*)d_in[4];
  const int*   node_atom = (const int*)d_in[5];
  const float* ele    = (const float*)d_in[6];
  const float* W_embed= (const float*)d_in[7];
  const float* W_edge = (const float*)d_in[8];
  const float* Wq = (const float*)d_in[9];
  const float* Wk = (const float*)d_in[10];
  const float* Wv = (const float*)d_in[11];
  const float* Wr1= (const float*)d_in[12];
  const float* Wr2= (const float*)d_in[13];
  const float* Wo = (const float*)d_in[14];
  const float* W1 = (const float*)d_in[15];
  const float* W2 = (const float*)d_in[16];
  const float* W_feat=(const float*)d_in[17];
  const float* hW1= (const float*)d_in[18];
  const float* hb1= (const float*)d_in[19];
  const float* hW2= (const float*)d_in[20];
  const float* hb2= (const float*)d_in[21];
  const float* hW3= (const float*)d_in[22];
  const float* hb3= (const float*)d_in[23];
  (void)n_in; (void)ws_size;

  const int E = in_sizes[1];
  const int N = in_sizes[4];
  const int G = out_size;

  // ---- workspace layout: peak ~90 MB ----
  char* base = (char*)d_ws;
  size_t off = 0;
  #define ALLOC(ty, name, count) ty* name = (ty*)(base + off); off = (off + (size_t)(count)*sizeof(ty) + 255) & ~(size_t)255;
  ALLOC(float, r2,    E)
  ALLOC(int,   src2,  E)
  ALLOC(int,   dst2,  E)
  ALLOC(u16,   ebf,   (size_t)E*64)
  ALLOC(u16,   vbf,   (size_t)E*64)
  ALLOC(float, exb,   (size_t)E*4)
  ALLOC(float, radtab,(size_t)6*RGROWS*4)
  ALLOC(u16,   hbf,   (size_t)N*64)
  ALLOC(u16,   aggbf, (size_t)N*64)
  ALLOC(u16,   xbf,   (size_t)N*64)
  ALLOC(float, Qt,    (size_t)N*64)
  ALLOC(float, xb,    (size_t)N*64)
  ALLOC(int,   deg,   N)
  ALLOC(int,   rowptr,N+1)
  ALLOC(int,   cursor,N)
  ALLOC(int,   csr,   E)
  ALLOC(float, pooled,G)
  // contiguous prep-region
  ALLOC(u16, ele_bf, 120*32)
  ALLOC(u16, WembT, 64*32)
  ALLOC(u16, WedgeT,64*160)
  ALLOC(u16, WqT,  6*64*64)
  ALLOC(u16, WkT,  6*64*64)
  ALLOC(u16, WvT,  6*64*64)
  ALLOC(u16, Wr1T, 6*64*64)
  ALLOC(u16, WoT,  6*64*64)
  ALLOC(u16, W1T,  6*256*64)
  ALLOC(u16, W2T,  6*64*256)
  ALLOC(u16, WfT,  512*64)
  ALLOC(u16, hW1T, 64*512)
  ALLOC(u16, hW2T, 64*64)
  #undef ALLOC
  // tail aliases into loop-dead regions:
  u16* featbf = ebf;          // 16 MB <= 32 MB
  u16* hh1    = (u16*)exb;    // 2 MB <= 4 MB

  auto cdiv = [](int a, int b){ return (a + b - 1)/b; };

  k_prep<<<cdiv(405248,256),256,0,stream>>>(ele, W_embed, W_edge, Wq, Wk, Wv, Wr1, Wo,
                                            W1, W2, W_feat, hW1, hW2, ele_bf);

  hipMemsetAsync(deg, 0, (size_t)N*sizeof(int), stream);
  hipMemsetAsync(pooled, 0, (size_t)G*sizeof(float), stream);

  k_count<<<cdiv(E,256),256,0,stream>>>(edge_dst, deg, E);
  k_scan<<<1,1024,0,stream>>>(deg, rowptr, cursor, N);
  k_scatter<<<cdiv(E,256),256,0,stream>>>(edge_dst, cursor, csr, E);
  k_edge_embed<<<E/64, 256, 0, stream>>>(csr, edge_src, edge_dst, node_atom, ele_bf, edge_vec,
                                         WedgeT, ebf, r2, src2, dst2, E);
  k_radtab<<<cdiv(RGROWS*4,256),256,0,stream>>>(Wr1T, Wr2, radtab);
  k_pre<<<N/64,256,0,stream>>>(node_atom, ele_bf, WembT, WqT, xb, hbf, Qt, N);

  for(int l=0; l<6; l++){
    k_kvrad<<<E/128,256,0,stream>>>(hbf, ebf, src2, dst2, Qt, r2, radtab + (size_t)l*RGROWS*4,
                                    WkT + l*4096, WvT + l*4096, vbf, exb, E);
    k_agg<<<cdiv(N,4),256,0,stream>>>(rowptr, exb, vbf, aggbf, N);
    k_mega<<<N/64,256,0,stream>>>(aggbf, WoT + l*4096, xb,
                                  W1T + l*16384, W2T + l*16384,
                                  WqT + ((l<5)?(l+1):0)*4096, Qt, hbf, xbf,
                                  (l==5)?1:0, (l<5)?1:0, N);
  }

  k_feat_ln<<<N/64,256,0,stream>>>(xbf, WfT, featbf, N);
  k_head1_ln<<<N/64,256,0,stream>>>(featbf, hW1T, hb1, hh1, N);
  k_head2_energy<<<N/64,256,0,stream>>>(hh1, hW2T, hb2, hW3, hb3, batch, pooled, N);
  k_out<<<cdiv(G,256),256,0,stream>>>(pooled, (float*)d_out, G);
}

// Round 17
// 660.213 us; speedup vs baseline: 1.2511x; 1.0222x over previous
//
#include <hip/hip_runtime.h>

typedef short s8v __attribute__((ext_vector_type(8)));
typedef float f32x4 __attribute__((ext_vector_type(4)));
typedef unsigned short u16;

__device__ __forceinline__ float bf2f(u16 h){
  union { unsigned u; float f; } v; v.u = ((unsigned)h) << 16; return v.f;
}
__device__ __forceinline__ u16 f2bf(float f){
  union { float f; unsigned u; } v; v.f = f;
  unsigned u = v.u;
  return (u16)((u + 0x7fffu + ((u >> 16) & 1u)) >> 16);
}
#define MFMA(a,b,c) __builtin_amdgcn_mfma_f32_16x16x32_bf16((a),(b),(c),0,0,0)

#define WREDUCE64(s) { s += __shfl_xor(s,1); s += __shfl_xor(s,2); s += __shfl_xor(s,4); \
                       s += __shfl_xor(s,8); s += __shfl_xor(s,16); s += __shfl_xor(s,32); }
#define QREDUCE16(s) { s += __shfl_xor(s,1); s += __shfl_xor(s,2); s += __shfl_xor(s,4); s += __shfl_xor(s,8); }

// 16-value butterfly within 16-lane quads: lane c (0..15) ends with sum-over-quad of val[c]
__device__ __forceinline__ float quad_butterfly16(float* val, int c){
  float v8[8], v4[4], v2[2];
  #pragma unroll
  for(int t=0;t<8;t++){
    float sent = (c&1) ? val[2*t] : val[2*t+1];
    float got = __shfl_xor(sent, 1);
    v8[t] = ((c&1) ? val[2*t+1] : val[2*t]) + got;
  }
  #pragma unroll
  for(int t=0;t<4;t++){
    float sent = ((c>>1)&1) ? v8[2*t] : v8[2*t+1];
    float got = __shfl_xor(sent, 2);
    v4[t] = (((c>>1)&1) ? v8[2*t+1] : v8[2*t]) + got;
  }
  #pragma unroll
  for(int t=0;t<2;t++){
    float sent = ((c>>2)&1) ? v4[2*t] : v4[2*t+1];
    float got = __shfl_xor(sent, 4);
    v2[t] = (((c>>2)&1) ? v4[2*t+1] : v4[2*t]) + got;
  }
  float sent = ((c>>3)&1) ? v2[0] : v2[1];
  float got = __shfl_xor(sent, 8);
  return (((c>>3)&1) ? v2[1] : v2[0]) + got;
}

// ---------------- ONE-SHOT prep: convert + all weight transposes (contiguous dst regions) ----------------
__global__ __launch_bounds__(256) void k_prep(const float* ele, const float* W_embed, const float* W_edge,
    const float* Wq, const float* Wk, const float* Wv, const float* Wr1, const float* Wo,
    const float* W1, const float* W2, const float* W_feat, const float* hW1, const float* hW2,
    u16* dst){
  int idx = blockIdx.x*256 + threadIdx.x;
  if(idx >= 405248) return;
  u16 v;
  if(idx < 3840){                    // ele convert
    v = f2bf(ele[idx]);
  } else if(idx < 5888){             // WembT: R=32,C=64,Rpad=32
    int l = idx - 3840;
    int cI = l >> 5, rI = l & 31;
    v = f2bf(W_embed[rI*64 + cI]);
  } else if(idx < 16128){            // WedgeT: R=137,C=64,Rpad=160
    int l = idx - 5888;
    int cI = l / 160, rI = l - cI*160;
    v = (rI < 137) ? f2bf(W_edge[rI*64 + cI]) : (u16)0;
  } else if(idx < 139008){           // Wq,Wk,Wv,Wr1,Wo: 5 x 6 x 64x64
    int l = idx - 16128;
    int which = l / 24576;
    int rem = l - which*24576;
    const float* src = (which==0)?Wq:(which==1)?Wk:(which==2)?Wv:(which==3)?Wr1:Wo;
    int b = rem >> 12;
    int r2 = rem & 4095;
    int cI = r2 >> 6, rI = r2 & 63;
    v = f2bf(src[b*4096 + rI*64 + cI]);
  } else if(idx < 237312){           // W1T: B=6,R=64,C=256,Rpad=64
    int l = idx - 139008;
    int b = l / 16384;
    int rem = l - b*16384;
    int cI = rem >> 6, rI = rem & 63;
    v = f2bf(W1[b*16384 + rI*256 + cI]);
  } else if(idx < 335616){           // W2T: B=6,R=256,C=64,Rpad=256
    int l = idx - 237312;
    int b = l / 16384;
    int rem = l - b*16384;
    int cI = rem >> 8, rI = rem & 255;
    v = f2bf(W2[b*16384 + rI*64 + cI]);
  } else if(idx < 368384){           // WfT: R=64,C=512,Rpad=64
    int l = idx - 335616;
    int cI = l >> 6, rI = l & 63;
    v = f2bf(W_feat[rI*512 + cI]);
  } else if(idx < 401152){           // hW1T: R=512,C=64,Rpad=512
    int l = idx - 368384;
    int cI = l >> 9, rI = l & 511;
    v = f2bf(hW1[rI*64 + cI]);
  } else {                           // hW2T: R=64,C=64
    int l = idx - 401152;
    int cI = l >> 6, rI = l & 63;
    v = f2bf(hW2[rI*64 + cI]);
  }
  dst[idx] = v;
}

// ---------------- CSR build ----------------
__global__ __launch_bounds__(256) void k_count(const int* dstI, int* deg, int E){
  int tid = blockIdx.x*256 + threadIdx.x;
  if(tid < E) atomicAdd(&deg[dstI[tid]], 1);
}
__global__ __launch_bounds__(1024) void k_scan(const int* deg, int* rowptr, int* cursor, int N){
  __shared__ int wsum[17];
  int tid = threadIdx.x;
  int per = (N + 1023) >> 10;
  int base = tid * per;
  int s = 0;
  for(int i=0;i<per;i++){ int idx = base+i; if(idx < N) s += deg[idx]; }
  int lane = tid & 63, wid = tid >> 6;
  int inc = s;
  for(int d=1; d<64; d<<=1){
    int t = __shfl_up(inc, d);
    if(lane >= d) inc += t;
  }
  if(lane == 63) wsum[wid+1] = inc;
  if(tid == 0) wsum[0] = 0;
  __syncthreads();
  if(tid == 0){ for(int w=1; w<=16; w++) wsum[w] += wsum[w-1]; }
  __syncthreads();
  int run = inc - s + wsum[wid];
  for(int i=0;i<per;i++){
    int idx = base + i;
    if(idx < N){ rowptr[idx] = run; cursor[idx] = run; run += deg[idx]; }
  }
  if(tid == 1023) rowptr[N] = wsum[16];
}
__global__ __launch_bounds__(256) void k_scatter(const int* dstI, int* cursor, int* csr, int E){
  int tid = blockIdx.x*256 + threadIdx.x;
  if(tid < E){
    int p = atomicAdd(&cursor[dstI[tid]], 1);
    csr[p] = tid;
  }
}

// ---------------- e = [nf_src, nf_dst, sh, rbf] @ W_edge, CSR order, TWO tiles per wave ----------------
__global__ __launch_bounds__(256) void k_edge_embed(const int* csr, const int* srcI, const int* dstI,
    const int* atom, const u16* ele, const float* evec, const u16* Bt,
    u16* ebf, float* r2, int* src2, int* dst2, int E){
  int wave = (blockIdx.x*256 + threadIdx.x) >> 6;
  int lane = threadIdx.x & 63;
  int base0 = wave*32; if(base0 >= E) return;
  int c = lane & 15, q = lane >> 4;
  s8v a[2][5];
  #pragma unroll
  for(int t=0;t<2;t++){
    int row0 = base0 + t*16;
    int p = row0 + c;
    int e = csr[p];
    int sn = srcI[e], dn = dstI[e];
    float vx = evec[(size_t)e*3+0];
    float vy = evec[(size_t)e*3+1];
    float vz = evec[(size_t)e*3+2];
    float r = sqrtf(vx*vx + vy*vy + vz*vz);
    if(q == 0){ r2[p] = r; src2[p] = sn; dst2[p] = dn; }
    float inv = 1.f/(r + 1e-12f);
    // u = edge_vec[:, [1,2,0]] / r -> x=v1, y=v2, z=v0
    float x = vy*inv, y = vz*inv, z = vx*inv;
    const float s3 = 1.7320508075688772f, s15 = 3.872983346207417f;
    const float s5h = 1.118033988749895f, s15h = 1.9364916731037085f;
    float sh[9];
    sh[0] = 1.f; sh[1] = s3*x; sh[2] = s3*y; sh[3] = s3*z;
    sh[4] = s15*x*y; sh[5] = s15*y*z; sh[6] = s5h*(3.f*z*z - 1.f);
    sh[7] = s15*x*z; sh[8] = s15h*(x*x - y*y);
    a[t][0] = *reinterpret_cast<const s8v*>(ele + (size_t)atom[sn]*32 + q*8);
    a[t][1] = *reinterpret_cast<const s8v*>(ele + (size_t)atom[dn]*32 + q*8);
    #pragma unroll
    for(int j=0;j<8;j++){
      int col = 64 + q*8 + j;
      u16 v;
      if(q == 0)            v = f2bf(sh[j]);
      else if(col < 73)     v = f2bf(sh[8]);
      else { float d = r - (10.f/63.f)*(float)(col-73); v = f2bf(__expf(-81.92f*d*d)); }
      a[t][2][j] = (short)v;
    }
    #pragma unroll
    for(int j=0;j<8;j++){
      float d = r - (10.f/63.f)*(float)(23 + q*8 + j);
      a[t][3][j] = (short)f2bf(__expf(-81.92f*d*d));
    }
    #pragma unroll
    for(int j=0;j<8;j++){
      int col = 128 + q*8 + j;
      u16 v = 0;
      if(col < 137){ float d = r - (10.f/63.f)*(float)(col-73); v = f2bf(__expf(-81.92f*d*d)); }
      a[t][4][j] = (short)v;
    }
  }
  #pragma unroll
  for(int ct=0; ct<4; ct++){
    s8v b[5];
    #pragma unroll
    for(int kc=0; kc<5; kc++)
      b[kc] = *reinterpret_cast<const s8v*>(Bt + (ct*16+c)*160 + kc*32 + q*8);
    #pragma unroll
    for(int t=0;t<2;t++){
      int row0 = base0 + t*16;
      f32x4 acc = {0.f,0.f,0.f,0.f};
      #pragma unroll
      for(int kc=0; kc<5; kc++) acc = MFMA(a[t][kc], b[kc], acc);
      #pragma unroll
      for(int r_=0;r_<4;r_++) ebf[(size_t)(row0+q*4+r_)*64 + ct*16 + c] = f2bf(acc[r_]);
    }
  }
}

// ---------------- one-shot: radial TABLE over r-grid [0,10], 4096 intervals, all 6 layers ----------------
#define RG 4096
#define RGROWS 4112
__global__ __launch_bounds__(256) void k_radtab(const u16* Wr1T, const float* Wr2, float* radtab){
  int wave = (blockIdx.x*256 + threadIdx.x) >> 6;
  int lane = threadIdx.x & 63;
  int row0 = wave*16; if(row0 >= RGROWS) return;
  int c = lane & 15, q = lane >> 4;
  float re = (10.f/RG)*(float)(row0 + c);
  s8v r0, r1;
  #pragma unroll
  for(int j=0;j<8;j++){
    float d0 = re - (10.f/63.f)*(float)(q*8+j);
    float d1 = re - (10.f/63.f)*(float)(32+q*8+j);
    r0[j] = (short)f2bf(__expf(-81.92f*d0*d0));
    r1[j] = (short)f2bf(__expf(-81.92f*d1*d1));
  }
  for(int l=0; l<6; l++){
    const u16* W1l = Wr1T + l*4096;
    const float4* wr2v = reinterpret_cast<const float4*>(Wr2 + l*256);
    float val[16];
    #pragma unroll
    for(int i=0;i<16;i++) val[i] = 0.f;
    #pragma unroll
    for(int ct=0; ct<4; ct++){
      s8v bw0 = *reinterpret_cast<const s8v*>(W1l + (ct*16+c)*64 + q*8);
      s8v bw1 = *reinterpret_cast<const s8v*>(W1l + (ct*16+c)*64 + 32 + q*8);
      f32x4 hacc = {0.f,0.f,0.f,0.f};
      hacc = MFMA(r0, bw0, hacc); hacc = MFMA(r1, bw1, hacc);
      float4 w2 = wr2v[ct*16 + c];
      #pragma unroll
      for(int r=0;r<4;r++){
        float y = hacc[r];
        float sv = y / (1.f + __expf(-y));
        val[r*4+0] += sv * w2.x;
        val[r*4+1] += sv * w2.y;
        val[r*4+2] += sv * w2.z;
        val[r*4+3] += sv * w2.w;
      }
    }
    float fin = quad_butterfly16(val, c);
    int row = row0 + q*4 + (c>>2);
    if(row <= RG)
      radtab[(size_t)l*RGROWS*4 + (size_t)row0*4 + lane] = fin;
  }
}

// ---------------- pre: x = ele[atom]@Wemb; h0 = LN(x); Q0 = h0@Wq0 (Qt layout) ----------------
__global__ __launch_bounds__(256) void k_pre(const int* atom, const u16* ele, const u16* WembT,
    const u16* WqT0, float* xb, u16* hbf, float* Qt, int M){
  __shared__ u16 ldsH[4][16*72];
  int widL = threadIdx.x >> 6;
  int wave = (blockIdx.x*256 + threadIdx.x) >> 6;
  int lane = threadIdx.x & 63;
  int row0 = wave*16; if(row0 >= M) return;
  int c = lane & 15, q = lane >> 4;
  u16* LH = ldsH[widL];
  int at = atom[row0 + c];
  s8v a = *reinterpret_cast<const s8v*>(ele + (size_t)at*32 + q*8);
  float nx[4][4];
  #pragma unroll
  for(int ct=0; ct<4; ct++){
    s8v b = *reinterpret_cast<const s8v*>(WembT + (ct*16+c)*32 + q*8);
    f32x4 acc = {0.f,0.f,0.f,0.f};
    acc = MFMA(a, b, acc);
    #pragma unroll
    for(int r=0;r<4;r++){
      xb[(size_t)(row0+q*4+r)*64 + ct*16 + c] = acc[r];
      nx[ct][r] = acc[r];
    }
  }
  #pragma unroll
  for(int r=0;r<4;r++){
    float s = nx[0][r]+nx[1][r]+nx[2][r]+nx[3][r];
    QREDUCE16(s);
    float m = s*(1.f/64.f);
    float vv = 0.f;
    #pragma unroll
    for(int ct=0;ct<4;ct++){ float d = nx[ct][r]-m; vv += d*d; }
    QREDUCE16(vv);
    float rs = rsqrtf(vv*(1.f/64.f) + 1e-6f);
    #pragma unroll
    for(int ct=0;ct<4;ct++){
      u16 hb = f2bf((nx[ct][r]-m)*rs);
      hbf[(size_t)(row0+q*4+r)*64 + ct*16 + c] = hb;
      LH[(q*4+r)*72 + ct*16 + c] = hb;
    }
  }
  s8v h0 = *reinterpret_cast<const s8v*>(LH + c*72 + q*8);
  s8v h1 = *reinterpret_cast<const s8v*>(LH + c*72 + 32 + q*8);
  #pragma unroll
  for(int ct=0; ct<4; ct++){
    s8v b0 = *reinterpret_cast<const s8v*>(WqT0 + (ct*16+c)*64 + q*8);
    s8v b1 = *reinterpret_cast<const s8v*>(WqT0 + (ct*16+c)*64 + 32 + q*8);
    f32x4 acc = {0.f,0.f,0.f,0.f};
    acc = MFMA(h0, b0, acc);
    acc = MFMA(h1, b1, acc);
    #pragma unroll
    for(int r=0;r<4;r++) Qt[(size_t)(row0+q*4+r)*64 + c*4 + ct] = acc[r];
  }
}

// ---------------- fused k,v MFMAs + qk logits + radial lerp + exp; TWO tiles per wave ----------------
__global__ __launch_bounds__(256) void k_kvrad(const u16* hbf, const u16* ebf,
    const int* src2, const int* dst2, const float* Qt, const float* r2, const float* radtab,
    const u16* WkT, const u16* WvT, u16* vbf, float* exb, int E){
  int wave = (blockIdx.x*256 + threadIdx.x) >> 6;
  int lane = threadIdx.x & 63;
  int base0 = wave*32;
  if(base0 >= E) return;
  int c = lane & 15, q = lane >> 4;
  s8v a0[2], a1[2];
  #pragma unroll
  for(int t=0;t<2;t++){
    int row0 = base0 + t*16;
    int sr = src2[row0 + c];
    s8v h0 = *reinterpret_cast<const s8v*>(hbf + (size_t)sr*64 + q*8);
    s8v h1 = *reinterpret_cast<const s8v*>(hbf + (size_t)sr*64 + 32 + q*8);
    s8v e0 = *reinterpret_cast<const s8v*>(ebf + (size_t)(row0+c)*64 + q*8);
    s8v e1 = *reinterpret_cast<const s8v*>(ebf + (size_t)(row0+c)*64 + 32 + q*8);
    #pragma unroll
    for(int j=0;j<8;j++){
      a0[t][j] = (short)f2bf(bf2f((u16)h0[j]) + bf2f((u16)e0[j]));
      a1[t][j] = (short)f2bf(bf2f((u16)h1[j]) + bf2f((u16)e1[j]));
    }
  }
  const float4* QtV = reinterpret_cast<const float4*>(Qt);
  float4 qv[2][4];
  #pragma unroll
  for(int t=0;t<2;t++)
    #pragma unroll
    for(int r=0;r<4;r++){
      int dr = dst2[base0 + t*16 + q*4 + r];
      qv[t][r] = QtV[(size_t)dr*16 + c];
    }
  float val[2][16];
  #pragma unroll
  for(int t=0;t<2;t++)
    #pragma unroll
    for(int i=0;i<16;i++) val[t][i] = 0.f;
  #pragma unroll
  for(int ct=0; ct<4; ct++){
    s8v bk0 = *reinterpret_cast<const s8v*>(WkT + (ct*16+c)*64 + q*8);
    s8v bk1 = *reinterpret_cast<const s8v*>(WkT + (ct*16+c)*64 + 32 + q*8);
    s8v bv0 = *reinterpret_cast<const s8v*>(WvT + (ct*16+c)*64 + q*8);
    s8v bv1 = *reinterpret_cast<const s8v*>(WvT + (ct*16+c)*64 + 32 + q*8);
    #pragma unroll
    for(int t=0;t<2;t++){
      int row0 = base0 + t*16;
      f32x4 kacc = {0.f,0.f,0.f,0.f};
      kacc = MFMA(a0[t], bk0, kacc); kacc = MFMA(a1[t], bk1, kacc);
      f32x4 vacc = {0.f,0.f,0.f,0.f};
      vacc = MFMA(a0[t], bv0, vacc); vacc = MFMA(a1[t], bv1, vacc);
      #pragma unroll
      for(int r=0;r<4;r++){
        vbf[(size_t)row0*64 + (r*4+ct)*64 + q*16 + c] = f2bf(vacc[r]);
        float qc = (ct==0)?qv[t][r].x:(ct==1)?qv[t][r].y:(ct==2)?qv[t][r].z:qv[t][r].w;
        val[t][r*4+ct] += 0.25f * kacc[r] * qc;
      }
    }
  }
  #pragma unroll
  for(int t=0;t<2;t++){
    int row0 = base0 + t*16;
    float qk = quad_butterfly16(val[t], c);   // lane c: (r=c>>2, h=c&3)
    int row = row0 + q*4 + (c>>2);
    float re = r2[row];
    float tt = re * ((float)RG/10.f);
    tt = fminf(fmaxf(tt, 0.f), (float)RG - 0.0001f);
    int i0 = (int)tt;
    float fr = tt - (float)i0;
    int h = c & 3;
    float lo = radtab[(size_t)i0*4 + h];
    float hi = radtab[(size_t)(i0+1)*4 + h];
    float logit = qk + lo + (hi - lo)*fr;
    exb[(size_t)row0*4 + lane] = (re < 10.f) ? __expf(logit) : 0.f;
  }
}

// ---------------- softmax-denominator + aggregation; edges contiguous per node ----------------
__global__ __launch_bounds__(256) void k_agg(const int* rowptr, const float* exb, const u16* vbf, u16* aggbf, int N){
  int wave = (blockIdx.x*256 + threadIdx.x) >> 6;
  int lane = threadIdx.x & 63;
  if(wave >= N) return;
  int s0 = rowptr[wave], s1 = rowptr[wave+1];
  float s[4] = {0.f,0.f,0.f,0.f};
  for(int p = s0 + lane; p < s1; p += 64){
    float4 ev = *reinterpret_cast<const float4*>(exb + (size_t)p*4);
    s[0] += ev.x; s[1] += ev.y; s[2] += ev.z; s[3] += ev.w;
  }
  #pragma unroll
  for(int i=0;i<4;i++){ WREDUCE64(s[i]); }
  int ep = lane >> 4, cc = lane & 15;
  int hh = cc >> 2;
  int swz = hh*64 + (cc&3)*4;
  float inv = 1.f/(s[hh] + 1e-9f);
  float a0=0.f, a1=0.f, a2=0.f, a3=0.f;
  for(int p = s0 + ep; p < s1; p += 4){
    int t = p & 15;
    size_t base = (size_t)(p & ~15)*64 + (size_t)((t&3)*256) + (size_t)((t>>2)*16) + swz;
    ushort4 v4 = *reinterpret_cast<const ushort4*>(vbf + base);
    float ex = exb[(size_t)p*4 + hh];
    a0 += ex*bf2f(v4.x); a1 += ex*bf2f(v4.y); a2 += ex*bf2f(v4.z); a3 += ex*bf2f(v4.w);
  }
  a0 += __shfl_xor(a0,16); a0 += __shfl_xor(a0,32);
  a1 += __shfl_xor(a1,16); a1 += __shfl_xor(a1,32);
  a2 += __shfl_xor(a2,16); a2 += __shfl_xor(a2,32);
  a3 += __shfl_xor(a3,16); a3 += __shfl_xor(a3,32);
  if(ep == 0){
    ushort4 o;
    o.x = f2bf(a0*inv); o.y = f2bf(a1*inv); o.z = f2bf(a2*inv); o.w = f2bf(a3*inv);
    *reinterpret_cast<ushort4*>(aggbf + (size_t)wave*64 + cc*4) = o;
  }
}

// ---------------- MEGA: x+=agg@Wo; LN; FFN1; FFN2+residual; LN->hbf; Q_next->Qt (no barriers) ----------------
__global__ __launch_bounds__(256) void k_mega(const u16* aggbf, const u16* WoT, float* x,
    const u16* W1T, const u16* W2T, const u16* WqTn, float* Qt, u16* hbf, u16* xbf,
    int writex, int haveQ, int M){
  __shared__ u16 ldsH[4][16*72];
  __shared__ u16 ldsT[4][16*264];
  int widL = threadIdx.x >> 6;
  int wave = (blockIdx.x*256 + threadIdx.x) >> 6;
  int lane = threadIdx.x & 63;
  int row0 = wave*16; if(row0 >= M) return;
  int c = lane & 15, q = lane >> 4;
  u16* LH = ldsH[widL];
  u16* LT = ldsT[widL];
  {
    s8v a0 = *reinterpret_cast<const s8v*>(aggbf + (size_t)(row0+c)*64 + q*8);
    s8v a1 = *reinterpret_cast<const s8v*>(aggbf + (size_t)(row0+c)*64 + 32 + q*8);
    float nx[4][4];
    #pragma unroll
    for(int ct=0; ct<4; ct++){
      s8v b0 = *reinterpret_cast<const s8v*>(WoT + (ct*16+c)*64 + q*8);
      s8v b1 = *reinterpret_cast<const s8v*>(WoT + (ct*16+c)*64 + 32 + q*8);
      f32x4 acc = {0.f,0.f,0.f,0.f};
      acc = MFMA(a0, b0, acc);
      acc = MFMA(a1, b1, acc);
      #pragma unroll
      for(int r=0;r<4;r++){
        size_t idx = (size_t)(row0+q*4+r)*64 + ct*16 + c;
        float t = x[idx] + acc[r];
        x[idx] = t;
        nx[ct][r] = t;
      }
    }
    #pragma unroll
    for(int r=0;r<4;r++){
      float s = nx[0][r]+nx[1][r]+nx[2][r]+nx[3][r];
      QREDUCE16(s);
      float m = s*(1.f/64.f);
      float vv = 0.f;
      #pragma unroll
      for(int ct=0;ct<4;ct++){ float d = nx[ct][r]-m; vv += d*d; }
      QREDUCE16(vv);
      float rs = rsqrtf(vv*(1.f/64.f) + 1e-6f);
      #pragma unroll
      for(int ct=0;ct<4;ct++)
        LH[(q*4+r)*72 + ct*16 + c] = f2bf((nx[ct][r]-m)*rs);
    }
  }
  {
    s8v h0 = *reinterpret_cast<const s8v*>(LH + c*72 + q*8);
    s8v h1 = *reinterpret_cast<const s8v*>(LH + c*72 + 32 + q*8);
    #pragma unroll
    for(int ct=0; ct<16; ct++){
      s8v b0 = *reinterpret_cast<const s8v*>(W1T + (ct*16+c)*64 + q*8);
      s8v b1 = *reinterpret_cast<const s8v*>(W1T + (ct*16+c)*64 + 32 + q*8);
      f32x4 acc = {0.f,0.f,0.f,0.f};
      acc = MFMA(h0, b0, acc);
      acc = MFMA(h1, b1, acc);
      #pragma unroll
      for(int r=0;r<4;r++){
        float y = acc[r];
        LT[(q*4+r)*264 + ct*16 + c] = f2bf(y / (1.f + __expf(-y)));
      }
    }
  }
  {
    s8v a[8];
    #pragma unroll
    for(int kc=0; kc<8; kc++)
      a[kc] = *reinterpret_cast<const s8v*>(LT + c*264 + kc*32 + q*8);
    float nx[4][4];
    #pragma unroll
    for(int ct=0; ct<4; ct++){
      f32x4 acc = {0.f,0.f,0.f,0.f};
      #pragma unroll
      for(int kc=0; kc<8; kc++){
        s8v b = *reinterpret_cast<const s8v*>(W2T + (ct*16+c)*256 + kc*32 + q*8);
        acc = MFMA(a[kc], b, acc);
      }
      #pragma unroll
      for(int r=0;r<4;r++){
        size_t idx = (size_t)(row0+q*4+r)*64 + ct*16 + c;
        float t = x[idx] + acc[r];
        x[idx] = t;
        nx[ct][r] = t;
        if(writex) xbf[idx] = f2bf(t);
      }
    }
    #pragma unroll
    for(int r=0;r<4;r++){
      float s = nx[0][r]+nx[1][r]+nx[2][r]+nx[3][r];
      QREDUCE16(s);
      float m = s*(1.f/64.f);
      float vv = 0.f;
      #pragma unroll
      for(int ct=0;ct<4;ct++){ float d = nx[ct][r]-m; vv += d*d; }
      QREDUCE16(vv);
      float rs = rsqrtf(vv*(1.f/64.f) + 1e-6f);
      #pragma unroll
      for(int ct=0;ct<4;ct++){
        u16 hb = f2bf((nx[ct][r]-m)*rs);
        hbf[(size_t)(row0+q*4+r)*64 + ct*16 + c] = hb;
        LH[(q*4+r)*72 + ct*16 + c] = hb;
      }
    }
  }
  if(haveQ){
    s8v h0 = *reinterpret_cast<const s8v*>(LH + c*72 + q*8);
    s8v h1 = *reinterpret_cast<const s8v*>(LH + c*72 + 32 + q*8);
    #pragma unroll
    for(int ct=0; ct<4; ct++){
      s8v b0 = *reinterpret_cast<const s8v*>(WqTn + (ct*16+c)*64 + q*8);
      s8v b1 = *reinterpret_cast<const s8v*>(WqTn + (ct*16+c)*64 + 32 + q*8);
      f32x4 acc = {0.f,0.f,0.f,0.f};
      acc = MFMA(h0, b0, acc);
      acc = MFMA(h1, b1, acc);
      #pragma unroll
      for(int r=0;r<4;r++) Qt[(size_t)(row0+q*4+r)*64 + c*4 + ct] = acc[r];
    }
  }
}

// ---------------- TAIL: feat@Wf + LN512; head1 K=512 + LN + relu; head2 + LN + relu + dot + pool ----------------
__global__ __launch_bounds__(256) void k_tail(const u16* xbf, const u16* WfT,
    const u16* hW1T, const float* hb1, const u16* hW2T, const float* hb2,
    const float* hW3, const float* hb3, const int* batch, float* pooled, int M){
  __shared__ u16 ldsF[4][16*522];
  __shared__ u16 ldsH[4][16*72];
  int widL = threadIdx.x >> 6;
  int wave = (blockIdx.x*256 + threadIdx.x) >> 6;
  int lane = threadIdx.x & 63;
  int row0 = wave*16; if(row0 >= M) return;
  int c = lane & 15, q = lane >> 4;
  u16* LF = ldsF[widL];
  u16* LH = ldsH[widL];
  // Phase 1: feat = x @ Wf; LN over 512 -> LF
  {
    s8v a0 = *reinterpret_cast<const s8v*>(xbf + (size_t)(row0+c)*64 + q*8);
    s8v a1 = *reinterpret_cast<const s8v*>(xbf + (size_t)(row0+c)*64 + 32 + q*8);
    float fa[32][4];
    #pragma unroll
    for(int ct=0; ct<32; ct++){
      s8v b0 = *reinterpret_cast<const s8v*>(WfT + (ct*16+c)*64 + q*8);
      s8v b1 = *reinterpret_cast<const s8v*>(WfT + (ct*16+c)*64 + 32 + q*8);
      f32x4 acc = {0.f,0.f,0.f,0.f};
      acc = MFMA(a0, b0, acc);
      acc = MFMA(a1, b1, acc);
      #pragma unroll
      for(int r=0;r<4;r++) fa[ct][r] = acc[r];
    }
    #pragma unroll
    for(int r=0;r<4;r++){
      float s = 0.f;
      #pragma unroll
      for(int ct=0;ct<32;ct++) s += fa[ct][r];
      QREDUCE16(s);
      float m = s*(1.f/512.f);
      float vv = 0.f;
      #pragma unroll
      for(int ct=0;ct<32;ct++){ float d = fa[ct][r]-m; vv += d*d; }
      QREDUCE16(vv);
      float rs = rsqrtf(vv*(1.f/512.f) + 1e-6f);
      #pragma unroll
      for(int ct=0;ct<32;ct++)
        LF[(q*4+r)*522 + ct*16 + c] = f2bf((fa[ct][r]-m)*rs);
    }
  }
  // Phase 2: y1 = featn @ hW1 + b1; LN + relu -> LH
  {
    float y[4][4];
    #pragma unroll
    for(int ct=0; ct<4; ct++){
      f32x4 acc = {0.f,0.f,0.f,0.f};
      #pragma unroll
      for(int kc=0; kc<16; kc++){
        s8v af = *reinterpret_cast<const s8v*>(LF + c*522 + kc*32 + q*8);
        s8v b = *reinterpret_cast<const s8v*>(hW1T + (size_t)(ct*16+c)*512 + kc*32 + q*8);
        acc = MFMA(af, b, acc);
      }
      float bi = hb1[ct*16+c];
      #pragma unroll
      for(int r=0;r<4;r++) y[ct][r] = acc[r] + bi;
    }
    #pragma unroll
    for(int r=0;r<4;r++){
      float s = y[0][r]+y[1][r]+y[2][r]+y[3][r];
      QREDUCE16(s);
      float m = s*(1.f/64.f);
      float vv = 0.f;
      #pragma unroll
      for(int ct=0;ct<4;ct++){ float d = y[ct][r]-m; vv += d*d; }
      QREDUCE16(vv);
      float rs = rsqrtf(vv*(1.f/64.f) + 1e-6f);
      #pragma unroll
      for(int ct=0;ct<4;ct++)
        LH[(q*4+r)*72 + ct*16 + c] = f2bf(fmaxf((y[ct][r]-m)*rs, 0.f));
    }
  }
  // Phase 3: y2 = hh1 @ hW2 + b2; LN + relu; dot hW3; pool
  {
    s8v a0 = *reinterpret_cast<const s8v*>(LH + c*72 + q*8);
    s8v a1 = *reinterpret_cast<const s8v*>(LH + c*72 + 32 + q*8);
    float y[4][4];
    #pragma unroll
    for(int ct=0; ct<4; ct++){
      s8v b0 = *reinterpret_cast<const s8v*>(hW2T + (ct*16+c)*64 + q*8);
      s8v b1 = *reinterpret_cast<const s8v*>(hW2T + (ct*16+c)*64 + 32 + q*8);
      f32x4 acc = {0.f,0.f,0.f,0.f};
      acc = MFMA(a0, b0, acc);
      acc = MFMA(a1, b1, acc);
      float bi = hb2[ct*16+c];
      #pragma unroll
      for(int r=0;r<4;r++) y[ct][r] = acc[r] + bi;
    }
    float w3[4];
    #pragma unroll
    for(int ct=0;ct<4;ct++) w3[ct] = hW3[ct*16+c];
    float ep[4];
    #pragma unroll
    for(int r=0;r<4;r++){
      float s = y[0][r]+y[1][r]+y[2][r]+y[3][r];
      QREDUCE16(s);
      float m = s*(1.f/64.f);
      float vv = 0.f;
      #pragma unroll
      for(int ct=0;ct<4;ct++){ float d = y[ct][r]-m; vv += d*d; }
      QREDUCE16(vv);
      float rs = rsqrtf(vv*(1.f/64.f) + 1e-6f);
      float e = 0.f;
      #pragma unroll
      for(int ct=0;ct<4;ct++) e += fmaxf((y[ct][r]-m)*rs, 0.f) * w3[ct];
      QREDUCE16(e);
      ep[r] = e;
    }
    if(c < 4){
      float ev = (c==0)?ep[0]:(c==1)?ep[1]:(c==2)?ep[2]:ep[3];
      int row = row0 + q*4 + c;
      atomicAdd(&pooled[batch[row]], ev + hb3[0]);
    }
  }
}

// ---------------- output f32 ----------------
__global__ __launch_bounds__(256) void k_out(const float* pooled, float* out, int G){
  int tid = blockIdx.x*256 + threadIdx.x;
  if(tid < G) out[tid] = pooled[tid] * 0.11785113019775793f; // 1/sqrt(72)
}

extern "C" void kernel_launch(void* const* d_in, const int* in_sizes, int n_in,
                              void* d_out, int out_size, void* d_ws, size_t ws_size,
                              hipStream_t stream){
  const int*   edge_src  = (const int*)d_in[1];
  const int*   edge_dst  = (const int*)d_in[2];
  const float* edge_vec  = (const float*)d_in[3];
  const int*   batch     = (const int*)d_in[4];
  const int*   node_atom = (const int*)d_in[5];
  const float* ele    = (const float*)d_in[6];
  const float* W_embed= (const float*)d_in[7];
  const float* W_edge = (const float*)d_in[8];
  const float* Wq = (const float*)d_in[9];
  const float* Wk = (const float*)d_in[10];
  const float* Wv = (const float*)d_in[11];
  const float* Wr1= (const float*)d_in[12];
  const float* Wr2= (const float*)d_in[13];
  const float* Wo = (const float*)d_in[14];
  const float* W1 = (const float*)d_in[15];
  const float* W2 = (const float*)d_in[16];
  const float* W_feat=(const float*)d_in[17];
  const float* hW1= (const float*)d_in[18];
  const float* hb1= (const float*)d_in[19];
  const float* hW2= (const float*)d_in[20];
  const float* hb2= (const float*)d_in[21];
  const float* hW3= (const float*)d_in[22];
  const float* hb3= (const float*)d_in[23];
  (void)n_in; (void)ws_size;

  const int E = in_sizes[1];
  const int N = in_sizes[4];
  const int G = out_size;

  // ---- workspace layout: peak ~74 MB ----
  char* base = (char*)d_ws;
  size_t off = 0;
  #define ALLOC(ty, name, count) ty* name = (ty*)(base + off); off = (off + (size_t)(count)*sizeof(ty) + 255) & ~(size_t)255;
  ALLOC(float, r2,    E)
  ALLOC(int,   src2,  E)
  ALLOC(int,   dst2,  E)
  ALLOC(u16,   ebf,   (size_t)E*64)
  ALLOC(u16,   vbf,   (size_t)E*64)
  ALLOC(float, exb,   (size_t)E*4)
  ALLOC(float, radtab,(size_t)6*RGROWS*4)
  ALLOC(u16,   hbf,   (size_t)N*64)
  ALLOC(u16,   aggbf, (size_t)N*64)
  ALLOC(u16,   xbf,   (size_t)N*64)
  ALLOC(float, Qt,    (size_t)N*64)
  ALLOC(float, xb,    (size_t)N*64)
  ALLOC(int,   deg,   N)
  ALLOC(int,   rowptr,N+1)
  ALLOC(int,   cursor,N)
  ALLOC(int,   csr,   E)
  ALLOC(float, pooled,G)
  // contiguous prep-region
  ALLOC(u16, ele_bf, 120*32)
  ALLOC(u16, WembT, 64*32)
  ALLOC(u16, WedgeT,64*160)
  ALLOC(u16, WqT,  6*64*64)
  ALLOC(u16, WkT,  6*64*64)
  ALLOC(u16, WvT,  6*64*64)
  ALLOC(u16, Wr1T, 6*64*64)
  ALLOC(u16, WoT,  6*64*64)
  ALLOC(u16, W1T,  6*256*64)
  ALLOC(u16, W2T,  6*64*256)
  ALLOC(u16, WfT,  512*64)
  ALLOC(u16, hW1T, 64*512)
  ALLOC(u16, hW2T, 64*64)
  #undef ALLOC

  auto cdiv = [](int a, int b){ return (a + b - 1)/b; };

  k_prep<<<cdiv(405248,256),256,0,stream>>>(ele, W_embed, W_edge, Wq, Wk, Wv, Wr1, Wo,
                                            W1, W2, W_feat, hW1, hW2, ele_bf);

  hipMemsetAsync(deg, 0, (size_t)N*sizeof(int), stream);
  hipMemsetAsync(pooled, 0, (size_t)G*sizeof(float), stream);

  k_count<<<cdiv(E,256),256,0,stream>>>(edge_dst, deg, E);
  k_scan<<<1,1024,0,stream>>>(deg, rowptr, cursor, N);
  k_scatter<<<cdiv(E,256),256,0,stream>>>(edge_dst, cursor, csr, E);
  k_edge_embed<<<E/128, 256, 0, stream>>>(csr, edge_src, edge_dst, node_atom, ele_bf, edge_vec,
                                          WedgeT, ebf, r2, src2, dst2, E);
  k_radtab<<<cdiv(RGROWS*4,256),256,0,stream>>>(Wr1T, Wr2, radtab);
  k_pre<<<N/64,256,0,stream>>>(node_atom, ele_bf, WembT, WqT, xb, hbf, Qt, N);

  for(int l=0; l<6; l++){
    k_kvrad<<<E/128,256,0,stream>>>(hbf, ebf, src2, dst2, Qt, r2, radtab + (size_t)l*RGROWS*4,
                                    WkT + l*4096, WvT + l*4096, vbf, exb, E);
    k_agg<<<cdiv(N,4),256,0,stream>>>(rowptr, exb, vbf, aggbf, N);
    k_mega<<<N/64,256,0,stream>>>(aggbf, WoT + l*4096, xb,
                                  W1T + l*16384, W2T + l*16384,
                                  WqT + ((l<5)?(l+1):0)*4096, Qt, hbf, xbf,
                                  (l==5)?1:0, (l<5)?1:0, N);
  }

  k_tail<<<N/64,256,0,stream>>>(xbf, WfT, hW1T, hb1, hW2T, hb2, hW3, hb3, batch, pooled, N);
  k_out<<<cdiv(G,256),256,0,stream>>>(pooled, (float*)d_out, G);
}